// Round 2
// baseline (940.633 us; speedup 1.0000x reference)
//
#include <hip/hip_runtime.h>
#include <hip/hip_bf16.h>
#include <math.h>

typedef __bf16 bf16;
typedef __attribute__((ext_vector_type(8))) __bf16 bf16x8;
typedef __attribute__((ext_vector_type(4))) float f32x4;

#define GLL(gp, lp) __builtin_amdgcn_global_load_lds( \
    (const __attribute__((address_space(1))) unsigned int*)(gp), \
    (__attribute__((address_space(3))) unsigned int*)(lp), 16, 0, 0)

#define S_BARRIER() __builtin_amdgcn_s_barrier()
#define WAIT_LGKM0() do { asm volatile("s_waitcnt lgkmcnt(0)" ::: "memory"); \
                          __builtin_amdgcn_sched_barrier(0); } while (0)
#define WAIT_VMC(n) do { asm volatile("s_waitcnt vmcnt(" #n ")" ::: "memory"); \
                         __builtin_amdgcn_sched_barrier(0); } while (0)

// ---------------------------------------------------------------------------
// Sizes: B=4, H=W=128 (n=16384/batch, 65536 rows total), C=512, HEADS=8, D=64
// ---------------------------------------------------------------------------

__device__ __forceinline__ bf16x8 cvt8(float4 a, float4 b) {
  bf16x8 o;
  o[0] = (bf16)a.x; o[1] = (bf16)a.y; o[2] = (bf16)a.z; o[3] = (bf16)a.w;
  o[4] = (bf16)b.x; o[5] = (bf16)b.y; o[6] = (bf16)b.z; o[7] = (bf16)b.w;
  return o;
}

// K0: x fp32 -> bf16; Wq|Wk|Wv fp32 -> concatenated bf16 (1536x512, N-major,
// K contiguous); zero attn accumulator + sumsq accumulators (ws is poisoned).
__global__ __launch_bounds__(256) void prep_kernel(
    const float* __restrict__ x, const float* __restrict__ Wq,
    const float* __restrict__ Wk, const float* __restrict__ Wv,
    bf16* __restrict__ xb, bf16* __restrict__ wqkv,
    float* __restrict__ zattn, float* __restrict__ ssq, float* __restrict__ ssk)
{
  const long XG = 33554432L / 8;   // x groups of 8
  const long WG = 262144L / 8;     // per-weight groups of 8
  long i = (long)blockIdx.x * 256 + threadIdx.x;
  if (i < XG) {
    const float4* xp = (const float4*)x;
    float4 a = xp[i * 2], b = xp[i * 2 + 1];
    *(bf16x8*)(xb + i * 8) = cvt8(a, b);
  } else if (i < XG + 3 * WG) {
    long j = i - XG;
    int w = (int)(j / WG);
    long r = j % WG;
    const float* src = (w == 0) ? Wq : ((w == 1) ? Wk : Wv);
    const float4* sp = (const float4*)src;
    float4 a = sp[r * 2], b = sp[r * 2 + 1];
    *(bf16x8*)(wqkv + (long)w * 262144 + r * 8) = cvt8(a, b);
  } else {
    long j = (i - XG - 3 * WG) * 8;   // float index into zero regions
    float4 z = make_float4(0.f, 0.f, 0.f, 0.f);
    if (j < 131072) {                 // attn accumulator 4*8*64*64
      *(float4*)(zattn + j) = z; *(float4*)(zattn + j + 4) = z;
    } else if (j < 133120) {          // sumsq_q 4*512
      long r = j - 131072; *(float4*)(ssq + r) = z; *(float4*)(ssq + r + 4) = z;
    } else {                          // sumsq_k 4*512
      long r = j - 133120; *(float4*)(ssk + r) = z; *(float4*)(ssk + r + 4) = z;
    }
  }
}

// ---------------------------------------------------------------------------
// bf16 NT-GEMM mainloop v4: 256x256 tile, BK=64, 512 threads = 8 waves
// (2M x 4N), per-wave 128x64 output = 8x4 MFMA 16x16x32 frags. 8-phase-class
// schedule (T3+T4+T5): per K-tile, 4 phases, each
//   { ds_read quadrant frags | stage 2 GLLs -> s_barrier -> lgkmcnt(0)
//     -> setprio(1) -> 16 MFMA -> setprio(0) -> s_barrier }
// Raw s_barrier (no __syncthreads vmcnt(0) drain); counted vmcnt(4) ONCE per
// K-tile (phase d): outstanding there = A(kt+1)[4] + B(kt+2)[4] = 8; waiting
// 4 guarantees tile kt+1 fully landed before its phase-a ds_reads.
// Staging ledger (write-after-read, all barrier-separated):
//   ph a/b: stage A(kt+1) -> other slot's As  (its previous A consumed at
//           prior tile's ph c; disjoint array from this phase's Bs reads)
//   ph c/d: stage B(kt+2) -> this slot's Bs   (this tile's B consumed ph a/b)
// LDS: As/Bs = 2 slots x 256 x 64 bf16 = 128 KiB total; 1 block/CU.
// Same XOR chunk swizzle as v3 (global-side source swizzle, measured
// conflict-free): LDS[row][slot] holds global chunk [row][slot ^ (row&7)].
// Accumulation order per acc element unchanged vs v3 (K ascending) ->
// bit-identical numerics.
// ---------------------------------------------------------------------------
__device__ __forceinline__ void gemm256_mainloop(
    const bf16* __restrict__ A, const bf16* __restrict__ B,
    int m0, int n0, bf16* As, bf16* Bs, f32x4 (&acc)[8][4])
{
  const int tid = threadIdx.x;
  const int lane = tid & 63, wave = tid >> 6;
  const int wy = wave >> 2, wx = wave & 3;
  const int srow = tid >> 3;                       // 0..63 per issue
  const int scol = ((tid & 7) ^ (srow & 7)) * 8;   // swizzled global column
  const bf16* ag = A + ((size_t)(m0 + srow) << 9) + scol;
  const bf16* bg = B + ((size_t)(n0 + srow) << 9) + scol;
  bf16* lA = As + wave * 512;   // GLL dest wave-base; HW adds lane*16B
  bf16* lB = Bs + wave * 512;
  const int mloc = lane & 15, kq = lane >> 4;

  // issue i covers rows i*64..i*64+63 of the 256-row panel; tile t = k0/64.
#define STG_A(t, i) GLL(ag + (size_t)(i) * 32768 + (t) * 64, \
                        lA + (((t) & 1) * 16384 + (i) * 4096))
#define STG_B(t, i) GLL(bg + (size_t)(i) * 32768 + (t) * 64, \
                        lB + (((t) & 1) * 16384 + (i) * 4096))

  // prologue: T0 fully (8 issues) + T1.B (4 issues); wait T0 landed.
#pragma unroll
  for (int i = 0; i < 4; ++i) STG_A(0, i);
#pragma unroll
  for (int i = 0; i < 4; ++i) STG_B(0, i);
#pragma unroll
  for (int i = 0; i < 4; ++i) STG_B(1, i);
  WAIT_VMC(4);
  S_BARRIER();

  bf16x8 af[4][2];        // current row-half A frags
  bf16x8 bfr[2][2][2];    // [ch][ct][kh], both col-halves held per K-tile

#pragma unroll
  for (int kt = 0; kt < 8; ++kt) {
    const int s = kt & 1;
#pragma unroll
    for (int ph = 0; ph < 4; ++ph) {
      const int rh = ph >> 1, ch = ph & 1;
      if (ch == 0) {      // ph a,c: (re)load A frags for this row-half
#pragma unroll
        for (int rt = 0; rt < 4; ++rt) {
          const int r = wy * 128 + rh * 64 + rt * 16 + mloc;
#pragma unroll
          for (int kh = 0; kh < 2; ++kh)
            af[rt][kh] = *(const bf16x8*)
                &As[s * 16384 + r * 64 + (((kh * 4 + kq) ^ (r & 7)) << 3)];
        }
      }
      if (ph < 2) {       // ph a: B cols 0..31; ph b: B cols 32..63
#pragma unroll
        for (int ct = 0; ct < 2; ++ct) {
          const int nr = wx * 64 + ch * 32 + ct * 16 + mloc;
#pragma unroll
          for (int kh = 0; kh < 2; ++kh)
            bfr[ch][ct][kh] = *(const bf16x8*)
                &Bs[s * 16384 + nr * 64 + (((kh * 4 + kq) ^ (nr & 7)) << 3)];
        }
      }
      if (ph == 0 && kt + 1 < 8) { STG_A(kt + 1, 0); STG_A(kt + 1, 1); }
      if (ph == 1 && kt + 1 < 8) { STG_A(kt + 1, 2); STG_A(kt + 1, 3); }
      if (ph == 2 && kt + 2 < 8) { STG_B(kt + 2, 0); STG_B(kt + 2, 1); }
      if (ph == 3 && kt + 2 < 8) { STG_B(kt + 2, 2); STG_B(kt + 2, 3); }
      if (ph == 3) {
        if (kt <= 5)      { WAIT_VMC(4); }  // A(kt+1) landed; B(kt+2) in flight
        else if (kt == 6) { WAIT_VMC(0); }  // tail: only A(7) outstanding
      }
      S_BARRIER();
      WAIT_LGKM0();
      __builtin_amdgcn_s_setprio(1);
#pragma unroll
      for (int rt = 0; rt < 4; ++rt)
#pragma unroll
        for (int ct = 0; ct < 2; ++ct)
#pragma unroll
          for (int kh = 0; kh < 2; ++kh)
            acc[rh * 4 + rt][ch * 2 + ct] = __builtin_amdgcn_mfma_f32_16x16x32_bf16(
                af[rt][kh], bfr[ch][ct][kh], acc[rh * 4 + rt][ch * 2 + ct], 0, 0, 0);
      __builtin_amdgcn_s_setprio(0);
      S_BARRIER();
    }
  }
#undef STG_A
#undef STG_B
}

// K1: QKV projection. N-cols [0,512)=q, [512,1024)=k, [1024,1536)=v (v scaled
// by illu). Outputs bf16 row-major (65536 x 512). Fused: column sum-of-squares
// of fp32 q/k accumulators (for the l2norm over n) via shuffle + atomicAdd.
// XCD swizzle: the 6 nt-siblings of an mt run on one XCD -> A panel L2-hot.
__global__ __launch_bounds__(512, 2) void gemm_qkv_kernel(
    const bf16* __restrict__ xb, const bf16* __restrict__ wqkv,
    const float* __restrict__ illu,
    bf16* __restrict__ qb, bf16* __restrict__ kb, bf16* __restrict__ vb,
    float* __restrict__ ssq, float* __restrict__ ssk)
{
  __shared__ __align__(16) bf16 As[32768];   // 2 slots x 256 x 64
  __shared__ __align__(16) bf16 Bs[32768];
  int bid = blockIdx.x;
  int xcd = bid & 7, s = bid >> 3;          // s in [0,192)
  int mt = xcd * 32 + s / 6, nt = s % 6;
  int m0 = mt * 256, n0 = nt * 256;
  f32x4 acc[8][4] = {};
  gemm256_mainloop(xb, wqkv, m0, n0, As, Bs, acc);

  int tid = threadIdx.x, lane = tid & 63, wave = tid >> 6;
  int wy = wave >> 2, wx = wave & 3;
  int r0 = m0 + wy * 128 + ((lane >> 4) << 2);
  int c0 = n0 + wx * 64 + (lane & 15);
  int region = n0 >> 9;   // 256-tile never crosses a 512-col boundary
  if (region < 2) {
    bf16* outp = region ? kb : qb;
    float* dst = (region ? ssk : ssq) + (m0 >> 14) * 512;
#pragma unroll
    for (int tj = 0; tj < 4; ++tj) {
      int lc = (c0 + tj * 16) & 511;
      float ss = 0.f;
#pragma unroll
      for (int ti = 0; ti < 8; ++ti) {
#pragma unroll
        for (int r = 0; r < 4; ++r) {
          float v = acc[ti][tj][r];
          ss += v * v;
          outp[((size_t)(r0 + ti * 16 + r) << 9) + lc] = (bf16)v;
        }
      }
      ss += __shfl_xor(ss, 16);
      ss += __shfl_xor(ss, 32);
      if ((lane >> 4) == 0) atomicAdd(dst + lc, ss);
    }
  } else {
#pragma unroll
    for (int tj = 0; tj < 4; ++tj) {
      int lc = (c0 + tj * 16) & 511;
#pragma unroll
      for (int ti = 0; ti < 8; ++ti) {
#pragma unroll
        for (int r = 0; r < 4; ++r) {
          size_t idx = ((size_t)(r0 + ti * 16 + r) << 9) + lc;
          vb[idx] = (bf16)(acc[ti][tj][r] * illu[idx]);
        }
      }
    }
  }
}

// K3: S[b,h,d,e] = sum_n k[b,n,h*64+d] * q[b,n,h*64+e]  (unnormalized).
// grid (32 bh, 16 n-splits); block computes full 64x64, atomicAdd partials.
__global__ __launch_bounds__(256) void attn_dots_kernel(
    const bf16* __restrict__ qb, const bf16* __restrict__ kb,
    float* __restrict__ attn)
{
  __shared__ __align__(16) float ks[32 * 68];
  __shared__ __align__(16) float qs[32 * 68];
  int bh = blockIdx.x, sp = blockIdx.y;
  int b = bh >> 3, h = bh & 7;
  size_t hb = ((size_t)b << 23) + (size_t)h * 64;
  const bf16* qp = qb + hb;
  const bf16* kp = kb + hb;
  int t = threadIdx.x;
  int srow = t >> 3, scg = (t & 7) * 8;
  int d0 = (t & 15) * 4, e0 = (t >> 4) * 4;
  float acc[16] = {0};
  int nb = sp * 1024;
  for (int c = 0; c < 1024; c += 32) {
    size_t off = ((size_t)(nb + c + srow) << 9) + scg;
    bf16x8 kv = *(const bf16x8*)(kp + off);
    bf16x8 qv = *(const bf16x8*)(qp + off);
    __syncthreads();   // previous chunk's readers done
    float* kd = &ks[srow * 68 + scg];
    float* qd = &qs[srow * 68 + scg];
#pragma unroll
    for (int i = 0; i < 8; i++) { kd[i] = (float)kv[i]; qd[i] = (float)qv[i]; }
    __syncthreads();
#pragma unroll 8
    for (int n = 0; n < 32; n++) {
      float4 kr = *(const float4*)&ks[n * 68 + d0];
      float4 qr = *(const float4*)&qs[n * 68 + e0];
      acc[0]  += kr.x * qr.x; acc[1]  += kr.x * qr.y; acc[2]  += kr.x * qr.z; acc[3]  += kr.x * qr.w;
      acc[4]  += kr.y * qr.x; acc[5]  += kr.y * qr.y; acc[6]  += kr.y * qr.z; acc[7]  += kr.y * qr.w;
      acc[8]  += kr.z * qr.x; acc[9]  += kr.z * qr.y; acc[10] += kr.z * qr.z; acc[11] += kr.z * qr.w;
      acc[12] += kr.w * qr.x; acc[13] += kr.w * qr.y; acc[14] += kr.w * qr.z; acc[15] += kr.w * qr.w;
    }
  }
  float* ap = attn + ((size_t)bh << 12);
#pragma unroll
  for (int i = 0; i < 4; i++)
#pragma unroll
    for (int j = 0; j < 4; j++)
      atomicAdd(&ap[(d0 + i) * 64 + (e0 + j)], acc[i * 4 + j]);
}

// K4a: logits = S * rescale[h] / (nk[d] * nq[e]); softmax over e. In place.
// one block per (bh, d) row -> 2048 independent waves.
__global__ __launch_bounds__(64) void softmax_kernel(
    float* __restrict__ attn, const float* __restrict__ ssq,
    const float* __restrict__ ssk, const float* __restrict__ rescale)
{
  int bh = blockIdx.x, d = blockIdx.y;
  int b = bh >> 3, h = bh & 7;
  int e = threadIdx.x;
  float nq = fmaxf(sqrtf(ssq[b * 512 + h * 64 + e]), 1e-12f);
  float nk = fmaxf(sqrtf(ssk[b * 512 + h * 64 + d]), 1e-12f);
  float* ap = attn + ((size_t)bh << 12) + d * 64;
  float v = ap[e] * rescale[h] / (nk * nq);
  float m = v;
  for (int o = 32; o > 0; o >>= 1) m = fmaxf(m, __shfl_xor(m, o));
  float ex = expf(v - m);
  float s = ex;
  for (int o = 32; o > 0; o >>= 1) s += __shfl_xor(s, o);
  ap[e] = ex / s;
}

// K4b: W_effT[b][co][h*64+e] = sum_d attn[b,h,d,e] * Wp[co, h*64+d]  (bf16).
// (exact reassociation of xo@Wp^T; out_c = v @ W_eff + bp)
__global__ __launch_bounds__(256) void weff_kernel(
    const float* __restrict__ attn, const float* __restrict__ Wp,
    bf16* __restrict__ wefT)
{
  int cog = blockIdx.x, h = blockIdx.y, b = blockIdx.z;
  __shared__ float at[4096];   // [d][e]
  __shared__ float wp[4096];   // [co_l][d]
  int t = threadIdx.x;
  const float* ap = attn + ((size_t)(b * 8 + h) << 12);
  for (int i = t; i < 4096; i += 256) at[i] = ap[i];
  for (int i = t; i < 4096; i += 256) {
    int r = i >> 6, d = i & 63;
    wp[i] = Wp[((size_t)(cog * 64 + r) << 9) + h * 64 + d];
  }
  __syncthreads();
  int co_l = (t & 15) * 4, e_l = (t >> 4) * 4;
  float acc[16] = {0};
  for (int d = 0; d < 64; d++) {
    float w0 = wp[(co_l + 0) * 64 + d];
    float w1 = wp[(co_l + 1) * 64 + d];
    float w2 = wp[(co_l + 2) * 64 + d];
    float w3 = wp[(co_l + 3) * 64 + d];
    float4 av = *(const float4*)&at[d * 64 + e_l];
    acc[0]  += w0 * av.x; acc[1]  += w0 * av.y; acc[2]  += w0 * av.z; acc[3]  += w0 * av.w;
    acc[4]  += w1 * av.x; acc[5]  += w1 * av.y; acc[6]  += w1 * av.z; acc[7]  += w1 * av.w;
    acc[8]  += w2 * av.x; acc[9]  += w2 * av.y; acc[10] += w2 * av.z; acc[11] += w2 * av.w;
    acc[12] += w3 * av.x; acc[13] += w3 * av.y; acc[14] += w3 * av.z; acc[15] += w3 * av.w;
  }
#pragma unroll
  for (int i = 0; i < 4; i++)
#pragma unroll
    for (int j = 0; j < 4; j++)
      wefT[((size_t)b << 18) + ((size_t)(cog * 64 + co_l + i) << 9) + h * 64 + e_l + j] =
          (bf16)acc[i * 4 + j];
}

// K5: out_c = v @ W_eff[b] + bp  -> d_out (fp32). Same 256^2 mainloop as K1.
__global__ __launch_bounds__(512, 2) void gemm_out_kernel(
    const bf16* __restrict__ vb, const bf16* __restrict__ wefT,
    const float* __restrict__ bp, float* __restrict__ out)
{
  __shared__ __align__(16) bf16 As[32768];
  __shared__ __align__(16) bf16 Bs[32768];
  int b = blockIdx.y;
  int bid = blockIdx.x;
  int xcd = bid & 7, s = bid >> 3;          // s in [0,16)
  int mt = xcd * 8 + (s >> 1), nt = s & 1;
  int m0 = mt * 256, n0 = nt * 256;
  const bf16* A = vb + ((size_t)b << 23);
  const bf16* B = wefT + ((size_t)b << 18);
  f32x4 acc[8][4] = {};
  gemm256_mainloop(A, B, m0, n0, As, Bs, acc);

  int tid = threadIdx.x, lane = tid & 63, wave = tid >> 6;
  int wy = wave >> 2, wx = wave & 3;
  int r0 = (b << 14) + m0 + wy * 128 + ((lane >> 4) << 2);
  int c0 = n0 + wx * 64 + (lane & 15);
#pragma unroll
  for (int ti = 0; ti < 8; ++ti) {
#pragma unroll
    for (int tj = 0; tj < 4; ++tj) {
      int lc = c0 + tj * 16;
      float bias = bp[lc];
#pragma unroll
      for (int r = 0; r < 4; ++r) {
        int grow = r0 + ti * 16 + r;
        out[((size_t)grow << 9) + lc] = acc[ti][tj][r] + bias;
      }
    }
  }
}

// K6: p = gelu_erf(dwconv3x3(v, pe1))  (NHWC, zero-pad SAME), bf16 out.
__global__ __launch_bounds__(256) void conv1_kernel(
    const bf16* __restrict__ vb, const float* __restrict__ pe1,
    bf16* __restrict__ pbuf)
{
  int b = blockIdx.y;
  int tile = blockIdx.x;
  int y0 = (tile >> 4) * 8, x0 = (tile & 15) * 8;
  int t = threadIdx.x;
  int cg = (t & 63) * 8, sp0 = t >> 6;
  float w[72];
#pragma unroll
  for (int i = 0; i < 8; i++)
#pragma unroll
    for (int k = 0; k < 9; k++)
      w[i * 9 + k] = pe1[(cg + i) * 9 + k];
  const bf16* vbase = vb + ((size_t)b << 23);
  bf16* pb = pbuf + ((size_t)b << 23);
  for (int s = sp0; s < 64; s += 4) {
    int y = y0 + (s >> 3), x = x0 + (s & 7);
    float a[8] = {0, 0, 0, 0, 0, 0, 0, 0};
#pragma unroll
    for (int ky = 0; ky < 3; ky++) {
      int yy = y + ky - 1;
      if (yy < 0 || yy >= 128) continue;
#pragma unroll
      for (int kx = 0; kx < 3; kx++) {
        int xx = x + kx - 1;
        if (xx < 0 || xx >= 128) continue;
        bf16x8 vv = *(const bf16x8*)&vbase[((size_t)(yy * 128 + xx) << 9) + cg];
#pragma unroll
        for (int i = 0; i < 8; i++) a[i] += (float)vv[i] * w[i * 9 + ky * 3 + kx];
      }
    }
    bf16x8 o;
#pragma unroll
    for (int i = 0; i < 8; i++) {
      float g = 0.5f * a[i] * (1.0f + erff(a[i] * 0.70710678118654752f));
      o[i] = (bf16)g;
    }
    *(bf16x8*)&pb[((size_t)(y * 128 + x) << 9) + cg] = o;
  }
}

// K7: out += dwconv3x3(p, pe2)   (read-modify-write fp32 d_out).
__global__ __launch_bounds__(256) void conv2_kernel(
    const bf16* __restrict__ pbuf, const float* __restrict__ pe2,
    float* __restrict__ out)
{
  int b = blockIdx.y;
  int tile = blockIdx.x;
  int y0 = (tile >> 4) * 8, x0 = (tile & 15) * 8;
  int t = threadIdx.x;
  int cg = (t & 63) * 8, sp0 = t >> 6;
  float w[72];
#pragma unroll
  for (int i = 0; i < 8; i++)
#pragma unroll
    for (int k = 0; k < 9; k++)
      w[i * 9 + k] = pe2[(cg + i) * 9 + k];
  const bf16* pb = pbuf + ((size_t)b << 23);
  float* ob = out + ((size_t)b << 23);
  for (int s = sp0; s < 64; s += 4) {
    int y = y0 + (s >> 3), x = x0 + (s & 7);
    float a[8] = {0, 0, 0, 0, 0, 0, 0, 0};
#pragma unroll
    for (int ky = 0; ky < 3; ky++) {
      int yy = y + ky - 1;
      if (yy < 0 || yy >= 128) continue;
#pragma unroll
      for (int kx = 0; kx < 3; kx++) {
        int xx = x + kx - 1;
        if (xx < 0 || xx >= 128) continue;
        bf16x8 vv = *(const bf16x8*)&pb[((size_t)(yy * 128 + xx) << 9) + cg];
#pragma unroll
        for (int i = 0; i < 8; i++) a[i] += (float)vv[i] * w[i * 9 + ky * 3 + kx];
      }
    }
    size_t oi = ((size_t)(y * 128 + x) << 9) + cg;
    float4 o0 = *(float4*)&ob[oi];
    float4 o1 = *(float4*)&ob[oi + 4];
    o0.x += a[0]; o0.y += a[1]; o0.z += a[2]; o0.w += a[3];
    o1.x += a[4]; o1.y += a[5]; o1.z += a[6]; o1.w += a[7];
    *(float4*)&ob[oi] = o0;
    *(float4*)&ob[oi + 4] = o1;
  }
}

extern "C" void kernel_launch(void* const* d_in, const int* in_sizes, int n_in,
                              void* d_out, int out_size, void* d_ws, size_t ws_size,
                              hipStream_t stream) {
  (void)in_sizes; (void)n_in; (void)out_size; (void)ws_size;
  const float* x       = (const float*)d_in[0];
  const float* illu    = (const float*)d_in[1];
  const float* Wq      = (const float*)d_in[2];
  const float* Wk      = (const float*)d_in[3];
  const float* Wv      = (const float*)d_in[4];
  const float* rescale = (const float*)d_in[5];
  const float* Wp      = (const float*)d_in[6];
  const float* bp      = (const float*)d_in[7];
  const float* pe1     = (const float*)d_in[8];
  const float* pe2     = (const float*)d_in[9];
  float* out = (float*)d_out;
  char* ws = (char*)d_ws;

  // workspace layout (bytes); total = 272,646,144
  bf16*  xb   = (bf16*)(ws);                      // 67,108,864  (reused as pbuf)
  bf16*  wqkv = (bf16*)(ws + 67108864);           //  1,572,864
  bf16*  qb   = (bf16*)(ws + 68681728);           // 67,108,864
  bf16*  kb   = (bf16*)(ws + 135790592);          // 67,108,864
  bf16*  vb   = (bf16*)(ws + 202899456);          // 67,108,864
  float* ssq  = (float*)(ws + 270008320);         //      8,192
  float* ssk  = (float*)(ws + 270016512);         //      8,192
  float* attn = (float*)(ws + 270024704);         //    524,288
  bf16*  wefT = (bf16*)(ws + 270548992);          //  2,097,152
  bf16*  pbuf = xb;                               // x dead after gemm_qkv

  prep_kernel<<<16834, 256, 0, stream>>>(x, Wq, Wk, Wv, xb, wqkv, attn, ssq, ssk);
  gemm_qkv_kernel<<<1536, 512, 0, stream>>>(xb, wqkv, illu, qb, kb, vb, ssq, ssk);
  attn_dots_kernel<<<dim3(32, 16), 256, 0, stream>>>(qb, kb, attn);
  softmax_kernel<<<dim3(32, 64), 64, 0, stream>>>(attn, ssq, ssk, rescale);
  weff_kernel<<<dim3(8, 8, 4), 256, 0, stream>>>(attn, Wp, wefT);
  gemm_out_kernel<<<dim3(128, 4), 512, 0, stream>>>(vb, wefT, bp, out);
  conv1_kernel<<<dim3(256, 4), 256, 0, stream>>>(vb, pe1, pbuf);
  conv2_kernel<<<dim3(256, 4), 256, 0, stream>>>(pbuf, pe2, out);
}

// Round 3
// 810.734 us; speedup vs baseline: 1.1602x; 1.1602x over previous
//
#include <hip/hip_runtime.h>
#include <hip/hip_bf16.h>
#include <math.h>

typedef __bf16 bf16;
typedef __attribute__((ext_vector_type(4))) __bf16 bf16x4;
typedef __attribute__((ext_vector_type(8))) __bf16 bf16x8;
typedef __attribute__((ext_vector_type(4))) float f32x4;

#define GLL(gp, lp) __builtin_amdgcn_global_load_lds( \
    (const __attribute__((address_space(1))) unsigned int*)(gp), \
    (__attribute__((address_space(3))) unsigned int*)(lp), 16, 0, 0)

#define WAIT_LGKM0() do { asm volatile("s_waitcnt lgkmcnt(0)" ::: "memory"); \
                          __builtin_amdgcn_sched_barrier(0); } while (0)
#define WAIT_VMC0() do { asm volatile("s_waitcnt vmcnt(0)" ::: "memory"); \
                         __builtin_amdgcn_sched_barrier(0); } while (0)

// ---------------------------------------------------------------------------
// Sizes: B=4, H=W=128 (n=16384/batch, 65536 rows total), C=512, HEADS=8, D=64
// ---------------------------------------------------------------------------

__device__ __forceinline__ bf16x8 cvt8(float4 a, float4 b) {
  bf16x8 o;
  o[0] = (bf16)a.x; o[1] = (bf16)a.y; o[2] = (bf16)a.z; o[3] = (bf16)a.w;
  o[4] = (bf16)b.x; o[5] = (bf16)b.y; o[6] = (bf16)b.z; o[7] = (bf16)b.w;
  return o;
}

// K0: x fp32 -> bf16; Wq|Wk|Wv fp32 -> concatenated bf16 (1536x512, N-major,
// K contiguous); zero attn accumulator + sumsq accumulators (ws is poisoned).
__global__ __launch_bounds__(256) void prep_kernel(
    const float* __restrict__ x, const float* __restrict__ Wq,
    const float* __restrict__ Wk, const float* __restrict__ Wv,
    bf16* __restrict__ xb, bf16* __restrict__ wqkv,
    float* __restrict__ zattn, float* __restrict__ ssq, float* __restrict__ ssk)
{
  const long XG = 33554432L / 8;   // x groups of 8
  const long WG = 262144L / 8;     // per-weight groups of 8
  long i = (long)blockIdx.x * 256 + threadIdx.x;
  if (i < XG) {
    const float4* xp = (const float4*)x;
    float4 a = xp[i * 2], b = xp[i * 2 + 1];
    *(bf16x8*)(xb + i * 8) = cvt8(a, b);
  } else if (i < XG + 3 * WG) {
    long j = i - XG;
    int w = (int)(j / WG);
    long r = j % WG;
    const float* src = (w == 0) ? Wq : ((w == 1) ? Wk : Wv);
    const float4* sp = (const float4*)src;
    float4 a = sp[r * 2], b = sp[r * 2 + 1];
    *(bf16x8*)(wqkv + (long)w * 262144 + r * 8) = cvt8(a, b);
  } else {
    long j = (i - XG - 3 * WG) * 8;   // float index into zero regions
    float4 z = make_float4(0.f, 0.f, 0.f, 0.f);
    if (j < 131072) {                 // attn accumulator 4*8*64*64
      *(float4*)(zattn + j) = z; *(float4*)(zattn + j + 4) = z;
    } else if (j < 133120) {          // sumsq_q 4*512
      long r = j - 131072; *(float4*)(ssq + r) = z; *(float4*)(ssq + r + 4) = z;
    } else {                          // sumsq_k 4*512
      long r = j - 133120; *(float4*)(ssk + r) = z; *(float4*)(ssk + r + 4) = z;
    }
  }
}

// ---------------------------------------------------------------------------
// bf16 NT-GEMM mainloop v3 (PROVEN, R1): A (Mx512 rm), B (Nx512 rm = B^T),
// 128x128 tile, BK=64, 256 threads = 4 waves, per-wave 64x64 quadrant as
// 4x4 MFMA 16x16x32 frags x 2 k-halves. Double-buffered K pipeline: issue
// next K-tile's 8 GLLs first, compute current, ONE __syncthreads per iter.
// XOR chunk swizzle on global source side -> conflict-free ds_read_b128.
// (R2's 256^2 8-phase port regressed: 1 blk/CU barrier exposure + L3 thrash.)
// ---------------------------------------------------------------------------
__device__ __forceinline__ void gemm_tile_mainloop(
    const bf16* __restrict__ A, const bf16* __restrict__ B,
    int m0, int n0, bf16* As, bf16* Bs, f32x4 acc[4][4])
{
  int tid = threadIdx.x;
  int lane = tid & 63, wave = tid >> 6;
  int wy = wave >> 1, wx = wave & 1;
  int srow = tid >> 3;                       // 0..31
  int scol = ((tid & 7) ^ (srow & 7)) * 8;   // swizzled global column
  const bf16* ag = A + ((size_t)(m0 + srow) << 9) + scol;
  const bf16* bg = B + ((size_t)(n0 + srow) << 9) + scol;
  bf16* lA = As + wave * 512;                // issue i adds 2048 (=4KB)
  bf16* lB = Bs + wave * 512;
  int mloc = lane & 15;
  int kq = lane >> 4;                        // quad -> k-chunk within half

  // prologue: stage K-tile 0 into buffer 0
#pragma unroll
  for (int i = 0; i < 4; i++) {
    GLL(ag + i * 16384, lA + i * 2048);
    GLL(bg + i * 16384, lB + i * 2048);
  }
  __syncthreads();   // vmcnt(0): buffer 0 ready

#pragma unroll
  for (int k0 = 0; k0 < 512; k0 += 64) {
    int cur = (k0 >> 6) & 1;
    if (k0 + 64 < 512) {
      int nb = cur ^ 1;
#pragma unroll
      for (int i = 0; i < 4; i++) {
        GLL(ag + (k0 + 64) + i * 16384, lA + nb * 8192 + i * 2048);
        GLL(bg + (k0 + 64) + i * 16384, lB + nb * 8192 + i * 2048);
      }
    }
    const bf16* Ac = As + (cur << 13);
    const bf16* Bc = Bs + (cur << 13);
#pragma unroll
    for (int kh = 0; kh < 2; kh++) {
      bf16x8 af[4], bfr[4];
      int logical = kh * 4 + kq;             // 16B chunk index in row
#pragma unroll
      for (int tt = 0; tt < 4; tt++) {
        int arow = wy * 64 + tt * 16 + mloc;
        af[tt] = *(const bf16x8*)&Ac[arow * 64 + (logical ^ (arow & 7)) * 8];
        int brow = wx * 64 + tt * 16 + mloc;
        bfr[tt] = *(const bf16x8*)&Bc[brow * 64 + (logical ^ (brow & 7)) * 8];
      }
#pragma unroll
      for (int ty = 0; ty < 4; ty++)
#pragma unroll
        for (int tx = 0; tx < 4; tx++)
          acc[ty][tx] = __builtin_amdgcn_mfma_f32_16x16x32_bf16(
              af[ty], bfr[tx], acc[ty][tx], 0, 0, 0);
    }
    __syncthreads();
  }
}

// K1: QKV projection. N-cols [0,512)=q, [512,1024)=k, [1024,1536)=v (v scaled
// by illu). q/k written TRANSPOSED: qbT/kbT[b][c][n] (c stride 16384, n
// contiguous) — sole consumer attn_dots needs n-contiguity for MFMA frags.
// The acc's 4 row-regs are 4 consecutive n -> single 8B store each.
// v stays [n][512] row-major (conv1/gemm_out need it). Fused column
// sum-of-squares of fp32 q/k accumulators via shuffle + atomicAdd.
__global__ __launch_bounds__(256) void gemm_qkv_kernel(
    const bf16* __restrict__ xb, const bf16* __restrict__ wqkv,
    const float* __restrict__ illu,
    bf16* __restrict__ qbT, bf16* __restrict__ kbT, bf16* __restrict__ vb,
    float* __restrict__ ssq, float* __restrict__ ssk)
{
  __shared__ __align__(16) bf16 As[16384];   // 2 x 8192 (double-buffered)
  __shared__ __align__(16) bf16 Bs[16384];
  int bid = blockIdx.x;
  int xcd = bid & 7, s = bid >> 3;          // s in [0,768)
  int mt = xcd * 64 + s / 12, nt = s % 12;
  int m0 = mt * 128, n0 = nt * 128;
  f32x4 acc[4][4] = {};
  gemm_tile_mainloop(xb, wqkv, m0, n0, As, Bs, acc);

  int tid = threadIdx.x, lane = tid & 63, wave = tid >> 6;
  int wy = wave >> 1, wx = wave & 1;
  int r0 = m0 + wy * 64 + ((lane >> 4) << 2);
  int c0 = n0 + wx * 64 + (lane & 15);
  int region = n0 >> 9;   // tile never crosses a 512-col boundary
  if (region < 2) {
    bf16* outp = region ? kbT : qbT;
    float* dst = (region ? ssk : ssq) + (m0 >> 14) * 512;
    int bb = r0 >> 14;            // batch (tile never crosses 16384 boundary)
    int nl0 = r0 & 16383;
#pragma unroll
    for (int tx = 0; tx < 4; tx++) {
      int lc = (c0 + tx * 16) & 511;
      bf16* colp = outp + (((size_t)bb << 23) + ((size_t)lc << 14));
      float ss = 0.f;
#pragma unroll
      for (int ty = 0; ty < 4; ty++) {
        f32x4 a = acc[ty][tx];
        ss += a[0] * a[0] + a[1] * a[1] + a[2] * a[2] + a[3] * a[3];
        bf16x4 o;
        o[0] = (bf16)a[0]; o[1] = (bf16)a[1]; o[2] = (bf16)a[2]; o[3] = (bf16)a[3];
        *(bf16x4*)&colp[nl0 + ty * 16] = o;
      }
      ss += __shfl_xor(ss, 16);
      ss += __shfl_xor(ss, 32);
      if ((lane >> 4) == 0) atomicAdd(dst + lc, ss);
    }
  } else {
#pragma unroll
    for (int tx = 0; tx < 4; tx++) {
      int lc = (c0 + tx * 16) & 511;
#pragma unroll
      for (int ty = 0; ty < 4; ty++) {
#pragma unroll
        for (int r = 0; r < 4; r++) {
          size_t idx = ((size_t)(r0 + ty * 16 + r) << 9) + lc;
          vb[idx] = (bf16)(acc[ty][tx][r] * illu[idx]);
        }
      }
    }
  }
}

// K3 v4: MFMA attn dots. S[b,h,d,e] = sum_n kbT[b,h*64+d,n] * qbT[b,h*64+e,n]
// — a pure NT-GEMM (both operands n-contiguous). grid (32 bh, 16 n-splits),
// 256 thr = 4 INDEPENDENT waves (no barriers): each wave owns 256 n in 4
// iters of 64, private 8KB k/q LDS tiles (single-buffered; GLL self-synced
// via vmcnt; 2 blocks/CU x 8 waves hides latency). Same XOR swizzle /
// fragment pattern as the gemm mainloop. atomicAdd fp32 partials (attn
// pre-zeroed by prep).
__global__ __launch_bounds__(256) void attn_dots_kernel(
    const bf16* __restrict__ qbT, const bf16* __restrict__ kbT,
    float* __restrict__ attn)
{
  __shared__ __align__(16) bf16 ks[4][4096];
  __shared__ __align__(16) bf16 qs[4][4096];
  int bh = blockIdx.x, sp = blockIdx.y;
  int b = bh >> 3, h = bh & 7;
  int t = threadIdx.x, lane = t & 63, w = t >> 6;
  size_t base = ((size_t)b << 23) + ((size_t)h << 20);   // [b][c=h*64][n]
  int n0 = sp * 1024 + w * 256;
  int srow = lane >> 3;                         // 8 rows per GLL issue
  int scol = ((lane & 7) ^ (srow & 7)) << 3;    // swizzled n-chunk (elements)
  const bf16* kg = kbT + base + (size_t)srow * 16384 + n0 + scol;
  const bf16* qg = qbT + base + (size_t)srow * 16384 + n0 + scol;
  bf16* lk = &ks[w][0];
  bf16* lq = &qs[w][0];
  int mloc = lane & 15, kq = lane >> 4;
  f32x4 acc[4][4] = {};

  for (int it = 0; it < 4; ++it) {
    WAIT_LGKM0();   // prior iter's ds_reads complete before LDS overwrite
#pragma unroll
    for (int i = 0; i < 8; ++i) {
      GLL(kg + it * 64 + (size_t)i * 131072, lk + i * 512);
      GLL(qg + it * 64 + (size_t)i * 131072, lq + i * 512);
    }
    WAIT_VMC0();    // staged tiles visible (same-wave, no barrier needed)
    bf16x8 af[4][2], bfq[4][2];
#pragma unroll
    for (int tt = 0; tt < 4; ++tt) {
      int r = tt * 16 + mloc;
#pragma unroll
      for (int kh = 0; kh < 2; ++kh) {
        int slot = (kh * 4 + kq) ^ (r & 7);
        af[tt][kh]  = *(const bf16x8*)&lk[r * 64 + slot * 8];
        bfq[tt][kh] = *(const bf16x8*)&lq[r * 64 + slot * 8];
      }
    }
#pragma unroll
    for (int kh = 0; kh < 2; ++kh)
#pragma unroll
      for (int ta = 0; ta < 4; ++ta)
#pragma unroll
        for (int tb = 0; tb < 4; ++tb)
          acc[ta][tb] = __builtin_amdgcn_mfma_f32_16x16x32_bf16(
              af[ta][kh], bfq[tb][kh], acc[ta][tb], 0, 0, 0);
  }
  float* ap = attn + ((size_t)bh << 12);
  int rr = (lane >> 4) << 2, cc = lane & 15;
#pragma unroll
  for (int ta = 0; ta < 4; ++ta)
#pragma unroll
    for (int tb = 0; tb < 4; ++tb)
#pragma unroll
      for (int r = 0; r < 4; ++r)
        atomicAdd(&ap[(ta * 16 + rr + r) * 64 + tb * 16 + cc], acc[ta][tb][r]);
}

// K4a: logits = S * rescale[h] / (nk[d] * nq[e]); softmax over e. In place.
// one block per (bh, d) row -> 2048 independent waves.
__global__ __launch_bounds__(64) void softmax_kernel(
    float* __restrict__ attn, const float* __restrict__ ssq,
    const float* __restrict__ ssk, const float* __restrict__ rescale)
{
  int bh = blockIdx.x, d = blockIdx.y;
  int b = bh >> 3, h = bh & 7;
  int e = threadIdx.x;
  float nq = fmaxf(sqrtf(ssq[b * 512 + h * 64 + e]), 1e-12f);
  float nk = fmaxf(sqrtf(ssk[b * 512 + h * 64 + d]), 1e-12f);
  float* ap = attn + ((size_t)bh << 12) + d * 64;
  float v = ap[e] * rescale[h] / (nk * nq);
  float m = v;
  for (int o = 32; o > 0; o >>= 1) m = fmaxf(m, __shfl_xor(m, o));
  float ex = expf(v - m);
  float s = ex;
  for (int o = 32; o > 0; o >>= 1) s += __shfl_xor(s, o);
  ap[e] = ex / s;
}

// K4b: W_effT[b][co][h*64+e] = sum_d attn[b,h,d,e] * Wp[co, h*64+d]  (bf16).
// (exact reassociation of xo@Wp^T; out_c = v @ W_eff + bp)
__global__ __launch_bounds__(256) void weff_kernel(
    const float* __restrict__ attn, const float* __restrict__ Wp,
    bf16* __restrict__ wefT)
{
  int cog = blockIdx.x, h = blockIdx.y, b = blockIdx.z;
  __shared__ float at[4096];   // [d][e]
  __shared__ float wp[4096];   // [co_l][d]
  int t = threadIdx.x;
  const float* ap = attn + ((size_t)(b * 8 + h) << 12);
  for (int i = t; i < 4096; i += 256) at[i] = ap[i];
  for (int i = t; i < 4096; i += 256) {
    int r = i >> 6, d = i & 63;
    wp[i] = Wp[((size_t)(cog * 64 + r) << 9) + h * 64 + d];
  }
  __syncthreads();
  int co_l = (t & 15) * 4, e_l = (t >> 4) * 4;
  float acc[16] = {0};
  for (int d = 0; d < 64; d++) {
    float w0 = wp[(co_l + 0) * 64 + d];
    float w1 = wp[(co_l + 1) * 64 + d];
    float w2 = wp[(co_l + 2) * 64 + d];
    float w3 = wp[(co_l + 3) * 64 + d];
    float4 av = *(const float4*)&at[d * 64 + e_l];
    acc[0]  += w0 * av.x; acc[1]  += w0 * av.y; acc[2]  += w0 * av.z; acc[3]  += w0 * av.w;
    acc[4]  += w1 * av.x; acc[5]  += w1 * av.y; acc[6]  += w1 * av.z; acc[7]  += w1 * av.w;
    acc[8]  += w2 * av.x; acc[9]  += w2 * av.y; acc[10] += w2 * av.z; acc[11] += w2 * av.w;
    acc[12] += w3 * av.x; acc[13] += w3 * av.y; acc[14] += w3 * av.z; acc[15] += w3 * av.w;
  }
#pragma unroll
  for (int i = 0; i < 4; i++)
#pragma unroll
    for (int j = 0; j < 4; j++)
      wefT[((size_t)b << 18) + ((size_t)(cog * 64 + co_l + i) << 9) + h * 64 + e_l + j] =
          (bf16)acc[i * 4 + j];
}

// K5: out_c = v @ W_eff[b] + bp  -> d_out (fp32). Same mainloop as K1.
// XCD swizzle: the 4 nt-siblings of an mt share one XCD.
__global__ __launch_bounds__(256) void gemm_out_kernel(
    const bf16* __restrict__ vb, const bf16* __restrict__ wefT,
    const float* __restrict__ bp, float* __restrict__ out)
{
  __shared__ __align__(16) bf16 As[16384];
  __shared__ __align__(16) bf16 Bs[16384];
  int b = blockIdx.y;
  int bid = blockIdx.x;
  int xcd = bid & 7, s = bid >> 3;          // s in [0,64)
  int mt = xcd * 16 + (s >> 2), nt = s & 3;
  int m0 = mt * 128, n0 = nt * 128;
  const bf16* A = vb + ((size_t)b << 23);
  const bf16* B = wefT + ((size_t)b << 18);
  f32x4 acc[4][4] = {};
  gemm_tile_mainloop(A, B, m0, n0, As, Bs, acc);

  int tid = threadIdx.x, lane = tid & 63, wave = tid >> 6;
  int wy = wave >> 1, wx = wave & 1;
  int r0 = (b << 14) + m0 + wy * 64 + ((lane >> 4) << 2);
  int c0 = n0 + wx * 64 + (lane & 15);
#pragma unroll
  for (int ty = 0; ty < 4; ty++) {
#pragma unroll
    for (int tx = 0; tx < 4; tx++) {
      int lc = c0 + tx * 16;
      float bias = bp[lc];
#pragma unroll
      for (int r = 0; r < 4; r++) {
        int grow = r0 + ty * 16 + r;
        out[((size_t)grow << 9) + lc] = acc[ty][tx][r] + bias;
      }
    }
  }
}

// K6: p = gelu_erf(dwconv3x3(v, pe1))  (NHWC, zero-pad SAME), bf16 out.
__global__ __launch_bounds__(256) void conv1_kernel(
    const bf16* __restrict__ vb, const float* __restrict__ pe1,
    bf16* __restrict__ pbuf)
{
  int b = blockIdx.y;
  int tile = blockIdx.x;
  int y0 = (tile >> 4) * 8, x0 = (tile & 15) * 8;
  int t = threadIdx.x;
  int cg = (t & 63) * 8, sp0 = t >> 6;
  float w[72];
#pragma unroll
  for (int i = 0; i < 8; i++)
#pragma unroll
    for (int k = 0; k < 9; k++)
      w[i * 9 + k] = pe1[(cg + i) * 9 + k];
  const bf16* vbase = vb + ((size_t)b << 23);
  bf16* pb = pbuf + ((size_t)b << 23);
  for (int s = sp0; s < 64; s += 4) {
    int y = y0 + (s >> 3), x = x0 + (s & 7);
    float a[8] = {0, 0, 0, 0, 0, 0, 0, 0};
#pragma unroll
    for (int ky = 0; ky < 3; ky++) {
      int yy = y + ky - 1;
      if (yy < 0 || yy >= 128) continue;
#pragma unroll
      for (int kx = 0; kx < 3; kx++) {
        int xx = x + kx - 1;
        if (xx < 0 || xx >= 128) continue;
        bf16x8 vv = *(const bf16x8*)&vbase[((size_t)(yy * 128 + xx) << 9) + cg];
#pragma unroll
        for (int i = 0; i < 8; i++) a[i] += (float)vv[i] * w[i * 9 + ky * 3 + kx];
      }
    }
    bf16x8 o;
#pragma unroll
    for (int i = 0; i < 8; i++) {
      float g = 0.5f * a[i] * (1.0f + erff(a[i] * 0.70710678118654752f));
      o[i] = (bf16)g;
    }
    *(bf16x8*)&pb[((size_t)(y * 128 + x) << 9) + cg] = o;
  }
}

// K7: out += dwconv3x3(p, pe2)   (read-modify-write fp32 d_out).
__global__ __launch_bounds__(256) void conv2_kernel(
    const bf16* __restrict__ pbuf, const float* __restrict__ pe2,
    float* __restrict__ out)
{
  int b = blockIdx.y;
  int tile = blockIdx.x;
  int y0 = (tile >> 4) * 8, x0 = (tile & 15) * 8;
  int t = threadIdx.x;
  int cg = (t & 63) * 8, sp0 = t >> 6;
  float w[72];
#pragma unroll
  for (int i = 0; i < 8; i++)
#pragma unroll
    for (int k = 0; k < 9; k++)
      w[i * 9 + k] = pe2[(cg + i) * 9 + k];
  const bf16* pb = pbuf + ((size_t)b << 23);
  float* ob = out + ((size_t)b << 23);
  for (int s = sp0; s < 64; s += 4) {
    int y = y0 + (s >> 3), x = x0 + (s & 7);
    float a[8] = {0, 0, 0, 0, 0, 0, 0, 0};
#pragma unroll
    for (int ky = 0; ky < 3; ky++) {
      int yy = y + ky - 1;
      if (yy < 0 || yy >= 128) continue;
#pragma unroll
      for (int kx = 0; kx < 3; kx++) {
        int xx = x + kx - 1;
        if (xx < 0 || xx >= 128) continue;
        bf16x8 vv = *(const bf16x8*)&pb[((size_t)(yy * 128 + xx) << 9) + cg];
#pragma unroll
        for (int i = 0; i < 8; i++) a[i] += (float)vv[i] * w[i * 9 + ky * 3 + kx];
      }
    }
    size_t oi = ((size_t)(y * 128 + x) << 9) + cg;
    float4 o0 = *(float4*)&ob[oi];
    float4 o1 = *(float4*)&ob[oi + 4];
    o0.x += a[0]; o0.y += a[1]; o0.z += a[2]; o0.w += a[3];
    o1.x += a[4]; o1.y += a[5]; o1.z += a[6]; o1.w += a[7];
    *(float4*)&ob[oi] = o0;
    *(float4*)&ob[oi + 4] = o1;
  }
}

extern "C" void kernel_launch(void* const* d_in, const int* in_sizes, int n_in,
                              void* d_out, int out_size, void* d_ws, size_t ws_size,
                              hipStream_t stream) {
  (void)in_sizes; (void)n_in; (void)out_size; (void)ws_size;
  const float* x       = (const float*)d_in[0];
  const float* illu    = (const float*)d_in[1];
  const float* Wq      = (const float*)d_in[2];
  const float* Wk      = (const float*)d_in[3];
  const float* Wv      = (const float*)d_in[4];
  const float* rescale = (const float*)d_in[5];
  const float* Wp      = (const float*)d_in[6];
  const float* bp      = (const float*)d_in[7];
  const float* pe1     = (const float*)d_in[8];
  const float* pe2     = (const float*)d_in[9];
  float* out = (float*)d_out;
  char* ws = (char*)d_ws;

  // workspace layout (bytes); total = 272,646,144
  bf16*  xb   = (bf16*)(ws);                      // 67,108,864  (reused as pbuf)
  bf16*  wqkv = (bf16*)(ws + 67108864);           //  1,572,864
  bf16*  qbT  = (bf16*)(ws + 68681728);           // 67,108,864  [b][c][n]
  bf16*  kbT  = (bf16*)(ws + 135790592);          // 67,108,864  [b][c][n]
  bf16*  vb   = (bf16*)(ws + 202899456);          // 67,108,864
  float* ssq  = (float*)(ws + 270008320);         //      8,192
  float* ssk  = (float*)(ws + 270016512);         //      8,192
  float* attn = (float*)(ws + 270024704);         //    524,288
  bf16*  wefT = (bf16*)(ws + 270548992);          //  2,097,152
  bf16*  pbuf = xb;                               // x dead after gemm_qkv

  prep_kernel<<<16834, 256, 0, stream>>>(x, Wq, Wk, Wv, xb, wqkv, attn, ssq, ssk);
  gemm_qkv_kernel<<<6144, 256, 0, stream>>>(xb, wqkv, illu, qbT, kbT, vb, ssq, ssk);
  attn_dots_kernel<<<dim3(32, 16), 256, 0, stream>>>(qbT, kbT, attn);
  softmax_kernel<<<dim3(32, 64), 64, 0, stream>>>(attn, ssq, ssk, rescale);
  weff_kernel<<<dim3(8, 8, 4), 256, 0, stream>>>(attn, Wp, wefT);
  gemm_out_kernel<<<dim3(512, 4), 256, 0, stream>>>(vb, wefT, bp, out);
  conv1_kernel<<<dim3(256, 4), 256, 0, stream>>>(vb, pe1, pbuf);
  conv2_kernel<<<dim3(256, 4), 256, 0, stream>>>(pbuf, pe2, out);
}

// Round 4
// 783.026 us; speedup vs baseline: 1.2013x; 1.0354x over previous
//
#include <hip/hip_runtime.h>
#include <hip/hip_bf16.h>
#include <math.h>

typedef __bf16 bf16;
typedef __attribute__((ext_vector_type(4))) __bf16 bf16x4;
typedef __attribute__((ext_vector_type(8))) __bf16 bf16x8;
typedef __attribute__((ext_vector_type(4))) float f32x4;

#define GLL(gp, lp) __builtin_amdgcn_global_load_lds( \
    (const __attribute__((address_space(1))) unsigned int*)(gp), \
    (__attribute__((address_space(3))) unsigned int*)(lp), 16, 0, 0)

#define WAIT_LGKM0() do { asm volatile("s_waitcnt lgkmcnt(0)" ::: "memory"); \
                          __builtin_amdgcn_sched_barrier(0); } while (0)
#define WAIT_VMC(n) do { asm volatile("s_waitcnt vmcnt(" #n ")" ::: "memory"); \
                         __builtin_amdgcn_sched_barrier(0); } while (0)
#define BARRIER_FENCE() asm volatile("s_barrier" ::: "memory")

// ---------------------------------------------------------------------------
// Sizes: B=4, H=W=128 (n=16384/batch, 65536 rows total), C=512, HEADS=8, D=64
// ---------------------------------------------------------------------------

__device__ __forceinline__ bf16x8 cvt8(float4 a, float4 b) {
  bf16x8 o;
  o[0] = (bf16)a.x; o[1] = (bf16)a.y; o[2] = (bf16)a.z; o[3] = (bf16)a.w;
  o[4] = (bf16)b.x; o[5] = (bf16)b.y; o[6] = (bf16)b.z; o[7] = (bf16)b.w;
  return o;
}

// K0: x fp32 -> bf16; Wq|Wk|Wv fp32 -> concatenated bf16 (1536x512, N-major,
// K contiguous); zero attn accumulator + sumsq accumulators (ws is poisoned).
__global__ __launch_bounds__(256) void prep_kernel(
    const float* __restrict__ x, const float* __restrict__ Wq,
    const float* __restrict__ Wk, const float* __restrict__ Wv,
    bf16* __restrict__ xb, bf16* __restrict__ wqkv,
    float* __restrict__ zattn, float* __restrict__ ssq, float* __restrict__ ssk)
{
  const long XG = 33554432L / 8;   // x groups of 8
  const long WG = 262144L / 8;     // per-weight groups of 8
  long i = (long)blockIdx.x * 256 + threadIdx.x;
  if (i < XG) {
    const float4* xp = (const float4*)x;
    float4 a = xp[i * 2], b = xp[i * 2 + 1];
    *(bf16x8*)(xb + i * 8) = cvt8(a, b);
  } else if (i < XG + 3 * WG) {
    long j = i - XG;
    int w = (int)(j / WG);
    long r = j % WG;
    const float* src = (w == 0) ? Wq : ((w == 1) ? Wk : Wv);
    const float4* sp = (const float4*)src;
    float4 a = sp[r * 2], b = sp[r * 2 + 1];
    *(bf16x8*)(wqkv + (long)w * 262144 + r * 8) = cvt8(a, b);
  } else {
    long j = (i - XG - 3 * WG) * 8;   // float index into zero regions
    float4 z = make_float4(0.f, 0.f, 0.f, 0.f);
    if (j < 131072) {                 // attn accumulator 4*8*64*64
      *(float4*)(zattn + j) = z; *(float4*)(zattn + j + 4) = z;
    } else if (j < 133120) {          // sumsq_q 4*512
      long r = j - 131072; *(float4*)(ssq + r) = z; *(float4*)(ssq + r + 4) = z;
    } else {                          // sumsq_k 4*512
      long r = j - 133120; *(float4*)(ssk + r) = z; *(float4*)(ssk + r + 4) = z;
    }
  }
}

// ---------------------------------------------------------------------------
// bf16 NT-GEMM mainloop v5: A (Mx512 rm), B (Nx512 rm = B^T), 128x128 tile,
// BK=32, 16 K-iters, 256 threads = 4 waves, per-wave 64x64 quadrant as
// 4x4 MFMA 16x16x32 frags (one k-chunk set per iter).
// 3-DEEP LDS pipeline, counted vmcnt (T4 sized for shallow K):
//   buffers 3 x (A 8KB + B 8KB) = 48KB -> 3 blocks/CU (vs v3's 2).
//   iter t: stage tile t+2 (4 GLLs) | ds_read buf[t%3] | 16 MFMA |
//           vmcnt(4) [tile t+1 landed; t+2 in flight -- never 0 mid-loop] |
//           s_barrier (asm, memory-fenced).
// Hazards: stage(t+2) overwrites buf[t-1], readers done before end-of-(t-1)
// barrier; cross-wave t+1 visibility = every wave's own vmcnt(4) + barrier.
// XOR chunk swizzle (slot space = 4): LDS[row][slot] holds global chunk
// [row][slot ^ (row&3)]; 64 lanes read 64 distinct chunks = contiguous 1KB
// -> conflict-free b128. Numerics: K ascending -> bit-identical to v3.
// ---------------------------------------------------------------------------
__device__ __forceinline__ void gemm_tile_mainloop(
    const bf16* __restrict__ A, const bf16* __restrict__ B,
    int m0, int n0, bf16* As, bf16* Bs, f32x4 acc[4][4])
{
  int tid = threadIdx.x;
  int lane = tid & 63, wave = tid >> 6;
  int wy = wave >> 1, wx = wave & 1;
  // staging: chunk c = issue*256 + tid; row = c>>2 (0..63/issue), slot = c&3.
  int srow = tid >> 2;                       // 0..63
  int scol = ((tid & 3) ^ (srow & 3)) * 8;   // swizzled global column (elems)
  const bf16* ag = A + ((size_t)(m0 + srow) << 9) + scol;
  const bf16* bg = B + ((size_t)(n0 + srow) << 9) + scol;
  bf16* lA = As + wave * 512;   // GLL dest: wave-base + lane*16B; issue +2048
  bf16* lB = Bs + wave * 512;
  int mloc = lane & 15;
  int kq = lane >> 4;                        // k-chunk 0..3 within BK=32

  // tile t: global k-offset t*32; buffer t%3 at element offset (t%3)*4096.
#define STG(t) do { \
    GLL(ag + (t) * 32,         lA + ((t) % 3) * 4096);        \
    GLL(ag + (t) * 32 + 32768, lA + ((t) % 3) * 4096 + 2048); \
    GLL(bg + (t) * 32,         lB + ((t) % 3) * 4096);        \
    GLL(bg + (t) * 32 + 32768, lB + ((t) % 3) * 4096 + 2048); \
  } while (0)

  // prologue: stage tiles 0 and 1; wait tile0 landed (4 of 8 outstanding).
  STG(0);
  STG(1);
  WAIT_VMC(4);
  BARRIER_FENCE();

#pragma unroll
  for (int t = 0; t < 16; ++t) {
    if (t + 2 < 16) STG(t + 2);
    const bf16* Ac = As + (t % 3) * 4096;
    const bf16* Bc = Bs + (t % 3) * 4096;
    bf16x8 af[4], bfr[4];
#pragma unroll
    for (int tt = 0; tt < 4; tt++) {
      int arow = wy * 64 + tt * 16 + mloc;
      af[tt] = *(const bf16x8*)&Ac[arow * 32 + ((kq ^ (arow & 3)) << 3)];
      int brow = wx * 64 + tt * 16 + mloc;
      bfr[tt] = *(const bf16x8*)&Bc[brow * 32 + ((kq ^ (brow & 3)) << 3)];
    }
    WAIT_LGKM0();
    __builtin_amdgcn_s_setprio(1);
#pragma unroll
    for (int ty = 0; ty < 4; ty++)
#pragma unroll
      for (int tx = 0; tx < 4; tx++)
        acc[ty][tx] = __builtin_amdgcn_mfma_f32_16x16x32_bf16(
            af[ty], bfr[tx], acc[ty][tx], 0, 0, 0);
    __builtin_amdgcn_s_setprio(0);
    if (t <= 13)      { WAIT_VMC(4); }   // tile t+1 landed; t+2 in flight
    else if (t == 14) { WAIT_VMC(0); }   // tail: only tile 15 outstanding
    if (t < 15) BARRIER_FENCE();
  }
#undef STG
}

// K1: QKV projection. N-cols [0,512)=q, [512,1024)=k, [1024,1536)=v (v scaled
// by illu). q/k written TRANSPOSED: qbT/kbT[b][c][n] (c stride 16384, n
// contiguous) — sole consumer attn_dots needs n-contiguity for MFMA frags.
// v stays [n][512] row-major (conv1/gemm_out need it). Fused column
// sum-of-squares of fp32 q/k accumulators via shuffle + atomicAdd.
__global__ __launch_bounds__(256, 3) void gemm_qkv_kernel(
    const bf16* __restrict__ xb, const bf16* __restrict__ wqkv,
    const float* __restrict__ illu,
    bf16* __restrict__ qbT, bf16* __restrict__ kbT, bf16* __restrict__ vb,
    float* __restrict__ ssq, float* __restrict__ ssk)
{
  __shared__ __align__(16) bf16 As[12288];   // 3 x 4096 (3-deep pipeline)
  __shared__ __align__(16) bf16 Bs[12288];
  int bid = blockIdx.x;
  int xcd = bid & 7, s = bid >> 3;          // s in [0,768)
  int mt = xcd * 64 + s / 12, nt = s % 12;
  int m0 = mt * 128, n0 = nt * 128;
  f32x4 acc[4][4] = {};
  gemm_tile_mainloop(xb, wqkv, m0, n0, As, Bs, acc);

  int tid = threadIdx.x, lane = tid & 63, wave = tid >> 6;
  int wy = wave >> 1, wx = wave & 1;
  int r0 = m0 + wy * 64 + ((lane >> 4) << 2);
  int c0 = n0 + wx * 64 + (lane & 15);
  int region = n0 >> 9;   // tile never crosses a 512-col boundary
  if (region < 2) {
    bf16* outp = region ? kbT : qbT;
    float* dst = (region ? ssk : ssq) + (m0 >> 14) * 512;
    int bb = r0 >> 14;            // batch (tile never crosses 16384 boundary)
    int nl0 = r0 & 16383;
#pragma unroll
    for (int tx = 0; tx < 4; tx++) {
      int lc = (c0 + tx * 16) & 511;
      bf16* colp = outp + (((size_t)bb << 23) + ((size_t)lc << 14));
      float ss = 0.f;
#pragma unroll
      for (int ty = 0; ty < 4; ty++) {
        f32x4 a = acc[ty][tx];
        ss += a[0] * a[0] + a[1] * a[1] + a[2] * a[2] + a[3] * a[3];
        bf16x4 o;
        o[0] = (bf16)a[0]; o[1] = (bf16)a[1]; o[2] = (bf16)a[2]; o[3] = (bf16)a[3];
        *(bf16x4*)&colp[nl0 + ty * 16] = o;
      }
      ss += __shfl_xor(ss, 16);
      ss += __shfl_xor(ss, 32);
      if ((lane >> 4) == 0) atomicAdd(dst + lc, ss);
    }
  } else {
#pragma unroll
    for (int tx = 0; tx < 4; tx++) {
      int lc = (c0 + tx * 16) & 511;
#pragma unroll
      for (int ty = 0; ty < 4; ty++) {
#pragma unroll
        for (int r = 0; r < 4; r++) {
          size_t idx = ((size_t)(r0 + ty * 16 + r) << 9) + lc;
          vb[idx] = (bf16)(acc[ty][tx][r] * illu[idx]);
        }
      }
    }
  }
}

// K3 v4: MFMA attn dots. S[b,h,d,e] = sum_n kbT[b,h*64+d,n] * qbT[b,h*64+e,n]
// — a pure NT-GEMM (both operands n-contiguous). grid (32 bh, 16 n-splits),
// 256 thr = 4 INDEPENDENT waves (no barriers): each wave owns 256 n in 4
// iters of 64, private 8KB k/q LDS tiles (single-buffered; GLL self-synced
// via vmcnt). atomicAdd fp32 partials (attn pre-zeroed by prep).
__global__ __launch_bounds__(256) void attn_dots_kernel(
    const bf16* __restrict__ qbT, const bf16* __restrict__ kbT,
    float* __restrict__ attn)
{
  __shared__ __align__(16) bf16 ks[4][4096];
  __shared__ __align__(16) bf16 qs[4][4096];
  int bh = blockIdx.x, sp = blockIdx.y;
  int b = bh >> 3, h = bh & 7;
  int t = threadIdx.x, lane = t & 63, w = t >> 6;
  size_t base = ((size_t)b << 23) + ((size_t)h << 20);   // [b][c=h*64][n]
  int n0 = sp * 1024 + w * 256;
  int srow = lane >> 3;                         // 8 rows per GLL issue
  int scol = ((lane & 7) ^ (srow & 7)) << 3;    // swizzled n-chunk (elements)
  const bf16* kg = kbT + base + (size_t)srow * 16384 + n0 + scol;
  const bf16* qg = qbT + base + (size_t)srow * 16384 + n0 + scol;
  bf16* lk = &ks[w][0];
  bf16* lq = &qs[w][0];
  int mloc = lane & 15, kq = lane >> 4;
  f32x4 acc[4][4] = {};

  for (int it = 0; it < 4; ++it) {
    WAIT_LGKM0();   // prior iter's ds_reads complete before LDS overwrite
#pragma unroll
    for (int i = 0; i < 8; ++i) {
      GLL(kg + it * 64 + (size_t)i * 131072, lk + i * 512);
      GLL(qg + it * 64 + (size_t)i * 131072, lq + i * 512);
    }
    WAIT_VMC(0);    // staged tiles visible (same-wave, no barrier needed)
    bf16x8 af[4][2], bfq[4][2];
#pragma unroll
    for (int tt = 0; tt < 4; ++tt) {
      int r = tt * 16 + mloc;
#pragma unroll
      for (int kh = 0; kh < 2; ++kh) {
        int slot = (kh * 4 + kq) ^ (r & 7);
        af[tt][kh]  = *(const bf16x8*)&lk[r * 64 + slot * 8];
        bfq[tt][kh] = *(const bf16x8*)&lq[r * 64 + slot * 8];
      }
    }
#pragma unroll
    for (int kh = 0; kh < 2; ++kh)
#pragma unroll
      for (int ta = 0; ta < 4; ++ta)
#pragma unroll
        for (int tb = 0; tb < 4; ++tb)
          acc[ta][tb] = __builtin_amdgcn_mfma_f32_16x16x32_bf16(
              af[ta][kh], bfq[tb][kh], acc[ta][tb], 0, 0, 0);
  }
  float* ap = attn + ((size_t)bh << 12);
  int rr = (lane >> 4) << 2, cc = lane & 15;
#pragma unroll
  for (int ta = 0; ta < 4; ++ta)
#pragma unroll
    for (int tb = 0; tb < 4; ++tb)
#pragma unroll
      for (int r = 0; r < 4; ++r)
        atomicAdd(&ap[(ta * 16 + rr + r) * 64 + tb * 16 + cc], acc[ta][tb][r]);
}

// K4a: logits = S * rescale[h] / (nk[d] * nq[e]); softmax over e. In place.
// one block per (bh, d) row -> 2048 independent waves.
__global__ __launch_bounds__(64) void softmax_kernel(
    float* __restrict__ attn, const float* __restrict__ ssq,
    const float* __restrict__ ssk, const float* __restrict__ rescale)
{
  int bh = blockIdx.x, d = blockIdx.y;
  int b = bh >> 3, h = bh & 7;
  int e = threadIdx.x;
  float nq = fmaxf(sqrtf(ssq[b * 512 + h * 64 + e]), 1e-12f);
  float nk = fmaxf(sqrtf(ssk[b * 512 + h * 64 + d]), 1e-12f);
  float* ap = attn + ((size_t)bh << 12) + d * 64;
  float v = ap[e] * rescale[h] / (nk * nq);
  float m = v;
  for (int o = 32; o > 0; o >>= 1) m = fmaxf(m, __shfl_xor(m, o));
  float ex = expf(v - m);
  float s = ex;
  for (int o = 32; o > 0; o >>= 1) s += __shfl_xor(s, o);
  ap[e] = ex / s;
}

// K4b: W_effT[b][co][h*64+e] = sum_d attn[b,h,d,e] * Wp[co, h*64+d]  (bf16).
// (exact reassociation of xo@Wp^T; out_c = v @ W_eff + bp)
__global__ __launch_bounds__(256) void weff_kernel(
    const float* __restrict__ attn, const float* __restrict__ Wp,
    bf16* __restrict__ wefT)
{
  int cog = blockIdx.x, h = blockIdx.y, b = blockIdx.z;
  __shared__ float at[4096];   // [d][e]
  __shared__ float wp[4096];   // [co_l][d]
  int t = threadIdx.x;
  const float* ap = attn + ((size_t)(b * 8 + h) << 12);
  for (int i = t; i < 4096; i += 256) at[i] = ap[i];
  for (int i = t; i < 4096; i += 256) {
    int r = i >> 6, d = i & 63;
    wp[i] = Wp[((size_t)(cog * 64 + r) << 9) + h * 64 + d];
  }
  __syncthreads();
  int co_l = (t & 15) * 4, e_l = (t >> 4) * 4;
  float acc[16] = {0};
  for (int d = 0; d < 64; d++) {
    float w0 = wp[(co_l + 0) * 64 + d];
    float w1 = wp[(co_l + 1) * 64 + d];
    float w2 = wp[(co_l + 2) * 64 + d];
    float w3 = wp[(co_l + 3) * 64 + d];
    float4 av = *(const float4*)&at[d * 64 + e_l];
    acc[0]  += w0 * av.x; acc[1]  += w0 * av.y; acc[2]  += w0 * av.z; acc[3]  += w0 * av.w;
    acc[4]  += w1 * av.x; acc[5]  += w1 * av.y; acc[6]  += w1 * av.z; acc[7]  += w1 * av.w;
    acc[8]  += w2 * av.x; acc[9]  += w2 * av.y; acc[10] += w2 * av.z; acc[11] += w2 * av.w;
    acc[12] += w3 * av.x; acc[13] += w3 * av.y; acc[14] += w3 * av.z; acc[15] += w3 * av.w;
  }
#pragma unroll
  for (int i = 0; i < 4; i++)
#pragma unroll
    for (int j = 0; j < 4; j++)
      wefT[((size_t)b << 18) + ((size_t)(cog * 64 + co_l + i) << 9) + h * 64 + e_l + j] =
          (bf16)acc[i * 4 + j];
}

// K5: out_c = v @ W_eff[b] + bp  -> d_out (fp32). Same v5 mainloop as K1.
// XCD swizzle: the 4 nt-siblings of an mt share one XCD.
__global__ __launch_bounds__(256, 3) void gemm_out_kernel(
    const bf16* __restrict__ vb, const bf16* __restrict__ wefT,
    const float* __restrict__ bp, float* __restrict__ out)
{
  __shared__ __align__(16) bf16 As[12288];
  __shared__ __align__(16) bf16 Bs[12288];
  int b = blockIdx.y;
  int bid = blockIdx.x;
  int xcd = bid & 7, s = bid >> 3;          // s in [0,64)
  int mt = xcd * 16 + (s >> 2), nt = s & 3;
  int m0 = mt * 128, n0 = nt * 128;
  const bf16* A = vb + ((size_t)b << 23);
  const bf16* B = wefT + ((size_t)b << 18);
  f32x4 acc[4][4] = {};
  gemm_tile_mainloop(A, B, m0, n0, As, Bs, acc);

  int tid = threadIdx.x, lane = tid & 63, wave = tid >> 6;
  int wy = wave >> 1, wx = wave & 1;
  int r0 = (b << 14) + m0 + wy * 64 + ((lane >> 4) << 2);
  int c0 = n0 + wx * 64 + (lane & 15);
#pragma unroll
  for (int ty = 0; ty < 4; ty++) {
#pragma unroll
    for (int tx = 0; tx < 4; tx++) {
      int lc = c0 + tx * 16;
      float bias = bp[lc];
#pragma unroll
      for (int r = 0; r < 4; r++) {
        int grow = r0 + ty * 16 + r;
        out[((size_t)grow << 9) + lc] = acc[ty][tx][r] + bias;
      }
    }
  }
}

// K6: p = gelu_erf(dwconv3x3(v, pe1))  (NHWC, zero-pad SAME), bf16 out.
__global__ __launch_bounds__(256) void conv1_kernel(
    const bf16* __restrict__ vb, const float* __restrict__ pe1,
    bf16* __restrict__ pbuf)
{
  int b = blockIdx.y;
  int tile = blockIdx.x;
  int y0 = (tile >> 4) * 8, x0 = (tile & 15) * 8;
  int t = threadIdx.x;
  int cg = (t & 63) * 8, sp0 = t >> 6;
  float w[72];
#pragma unroll
  for (int i = 0; i < 8; i++)
#pragma unroll
    for (int k = 0; k < 9; k++)
      w[i * 9 + k] = pe1[(cg + i) * 9 + k];
  const bf16* vbase = vb + ((size_t)b << 23);
  bf16* pb = pbuf + ((size_t)b << 23);
  for (int s = sp0; s < 64; s += 4) {
    int y = y0 + (s >> 3), x = x0 + (s & 7);
    float a[8] = {0, 0, 0, 0, 0, 0, 0, 0};
#pragma unroll
    for (int ky = 0; ky < 3; ky++) {
      int yy = y + ky - 1;
      if (yy < 0 || yy >= 128) continue;
#pragma unroll
      for (int kx = 0; kx < 3; kx++) {
        int xx = x + kx - 1;
        if (xx < 0 || xx >= 128) continue;
        bf16x8 vv = *(const bf16x8*)&vbase[((size_t)(yy * 128 + xx) << 9) + cg];
#pragma unroll
        for (int i = 0; i < 8; i++) a[i] += (float)vv[i] * w[i * 9 + ky * 3 + kx];
      }
    }
    bf16x8 o;
#pragma unroll
    for (int i = 0; i < 8; i++) {
      float g = 0.5f * a[i] * (1.0f + erff(a[i] * 0.70710678118654752f));
      o[i] = (bf16)g;
    }
    *(bf16x8*)&pb[((size_t)(y * 128 + x) << 9) + cg] = o;
  }
}

// K7: out += dwconv3x3(p, pe2)   (read-modify-write fp32 d_out).
__global__ __launch_bounds__(256) void conv2_kernel(
    const bf16* __restrict__ pbuf, const float* __restrict__ pe2,
    float* __restrict__ out)
{
  int b = blockIdx.y;
  int tile = blockIdx.x;
  int y0 = (tile >> 4) * 8, x0 = (tile & 15) * 8;
  int t = threadIdx.x;
  int cg = (t & 63) * 8, sp0 = t >> 6;
  float w[72];
#pragma unroll
  for (int i = 0; i < 8; i++)
#pragma unroll
    for (int k = 0; k < 9; k++)
      w[i * 9 + k] = pe2[(cg + i) * 9 + k];
  const bf16* pb = pbuf + ((size_t)b << 23);
  float* ob = out + ((size_t)b << 23);
  for (int s = sp0; s < 64; s += 4) {
    int y = y0 + (s >> 3), x = x0 + (s & 7);
    float a[8] = {0, 0, 0, 0, 0, 0, 0, 0};
#pragma unroll
    for (int ky = 0; ky < 3; ky++) {
      int yy = y + ky - 1;
      if (yy < 0 || yy >= 128) continue;
#pragma unroll
      for (int kx = 0; kx < 3; kx++) {
        int xx = x + kx - 1;
        if (xx < 0 || xx >= 128) continue;
        bf16x8 vv = *(const bf16x8*)&pb[((size_t)(yy * 128 + xx) << 9) + cg];
#pragma unroll
        for (int i = 0; i < 8; i++) a[i] += (float)vv[i] * w[i * 9 + ky * 3 + kx];
      }
    }
    size_t oi = ((size_t)(y * 128 + x) << 9) + cg;
    float4 o0 = *(float4*)&ob[oi];
    float4 o1 = *(float4*)&ob[oi + 4];
    o0.x += a[0]; o0.y += a[1]; o0.z += a[2]; o0.w += a[3];
    o1.x += a[4]; o1.y += a[5]; o1.z += a[6]; o1.w += a[7];
    *(float4*)&ob[oi] = o0;
    *(float4*)&ob[oi + 4] = o1;
  }
}

extern "C" void kernel_launch(void* const* d_in, const int* in_sizes, int n_in,
                              void* d_out, int out_size, void* d_ws, size_t ws_size,
                              hipStream_t stream) {
  (void)in_sizes; (void)n_in; (void)out_size; (void)ws_size;
  const float* x       = (const float*)d_in[0];
  const float* illu    = (const float*)d_in[1];
  const float* Wq      = (const float*)d_in[2];
  const float* Wk      = (const float*)d_in[3];
  const float* Wv      = (const float*)d_in[4];
  const float* rescale = (const float*)d_in[5];
  const float* Wp      = (const float*)d_in[6];
  const float* bp      = (const float*)d_in[7];
  const float* pe1     = (const float*)d_in[8];
  const float* pe2     = (const float*)d_in[9];
  float* out = (float*)d_out;
  char* ws = (char*)d_ws;

  // workspace layout (bytes); total = 272,646,144
  bf16*  xb   = (bf16*)(ws);                      // 67,108,864  (reused as pbuf)
  bf16*  wqkv = (bf16*)(ws + 67108864);           //  1,572,864
  bf16*  qbT  = (bf16*)(ws + 68681728);           // 67,108,864  [b][c][n]
  bf16*  kbT  = (bf16*)(ws + 135790592);          // 67,108,864  [b][c][n]
  bf16*  vb   = (bf16*)(ws + 202899456);          // 67,108,864
  float* ssq  = (float*)(ws + 270008320);         //      8,192
  float* ssk  = (float*)(ws + 270016512);         //      8,192
  float* attn = (float*)(ws + 270024704);         //    524,288
  bf16*  wefT = (bf16*)(ws + 270548992);          //  2,097,152
  bf16*  pbuf = xb;                               // x dead after gemm_qkv

  prep_kernel<<<16834, 256, 0, stream>>>(x, Wq, Wk, Wv, xb, wqkv, attn, ssq, ssk);
  gemm_qkv_kernel<<<6144, 256, 0, stream>>>(xb, wqkv, illu, qbT, kbT, vb, ssq, ssk);
  attn_dots_kernel<<<dim3(32, 16), 256, 0, stream>>>(qbT, kbT, attn);
  softmax_kernel<<<dim3(32, 64), 64, 0, stream>>>(attn, ssq, ssk, rescale);
  weff_kernel<<<dim3(8, 8, 4), 256, 0, stream>>>(attn, Wp, wefT);
  gemm_out_kernel<<<dim3(512, 4), 256, 0, stream>>>(vb, wefT, bp, out);
  conv1_kernel<<<dim3(256, 4), 256, 0, stream>>>(vb, pe1, pbuf);
  conv2_kernel<<<dim3(256, 4), 256, 0, stream>>>(pbuf, pe2, out);
}

// Round 5
// 741.490 us; speedup vs baseline: 1.2686x; 1.0560x over previous
//
#include <hip/hip_runtime.h>
#include <hip/hip_bf16.h>
#include <math.h>

typedef __bf16 bf16;
typedef __attribute__((ext_vector_type(4))) __bf16 bf16x4;
typedef __attribute__((ext_vector_type(8))) __bf16 bf16x8;
typedef __attribute__((ext_vector_type(4))) float f32x4;

#define GLL(gp, lp) __builtin_amdgcn_global_load_lds( \
    (const __attribute__((address_space(1))) unsigned int*)(gp), \
    (__attribute__((address_space(3))) unsigned int*)(lp), 16, 0, 0)

#define WAIT_LGKM0() do { asm volatile("s_waitcnt lgkmcnt(0)" ::: "memory"); \
                          __builtin_amdgcn_sched_barrier(0); } while (0)
#define WAIT_VMC(n) do { asm volatile("s_waitcnt vmcnt(" #n ")" ::: "memory"); \
                         __builtin_amdgcn_sched_barrier(0); } while (0)
#define BARRIER_FENCE() asm volatile("s_barrier" ::: "memory")

// ---------------------------------------------------------------------------
// Sizes: B=4, H=W=128 (n=16384/batch, 65536 rows total), C=512, HEADS=8, D=64
// ---------------------------------------------------------------------------

__device__ __forceinline__ bf16x8 cvt8(float4 a, float4 b) {
  bf16x8 o;
  o[0] = (bf16)a.x; o[1] = (bf16)a.y; o[2] = (bf16)a.z; o[3] = (bf16)a.w;
  o[4] = (bf16)b.x; o[5] = (bf16)b.y; o[6] = (bf16)b.z; o[7] = (bf16)b.w;
  return o;
}

// K0: x fp32 -> bf16; Wq|Wk|Wv fp32 -> concatenated bf16 (1536x512, N-major,
// K contiguous); zero attn accumulator + sumsq accumulators (ws is poisoned).
__global__ __launch_bounds__(256) void prep_kernel(
    const float* __restrict__ x, const float* __restrict__ Wq,
    const float* __restrict__ Wk, const float* __restrict__ Wv,
    bf16* __restrict__ xb, bf16* __restrict__ wqkv,
    float* __restrict__ zattn, float* __restrict__ ssq, float* __restrict__ ssk)
{
  const long XG = 33554432L / 8;   // x groups of 8
  const long WG = 262144L / 8;     // per-weight groups of 8
  long i = (long)blockIdx.x * 256 + threadIdx.x;
  if (i < XG) {
    const float4* xp = (const float4*)x;
    float4 a = xp[i * 2], b = xp[i * 2 + 1];
    *(bf16x8*)(xb + i * 8) = cvt8(a, b);
  } else if (i < XG + 3 * WG) {
    long j = i - XG;
    int w = (int)(j / WG);
    long r = j % WG;
    const float* src = (w == 0) ? Wq : ((w == 1) ? Wk : Wv);
    const float4* sp = (const float4*)src;
    float4 a = sp[r * 2], b = sp[r * 2 + 1];
    *(bf16x8*)(wqkv + (long)w * 262144 + r * 8) = cvt8(a, b);
  } else {
    long j = (i - XG - 3 * WG) * 8;   // float index into zero regions
    float4 z = make_float4(0.f, 0.f, 0.f, 0.f);
    if (j < 131072) {                 // attn accumulator 4*8*64*64
      *(float4*)(zattn + j) = z; *(float4*)(zattn + j + 4) = z;
    } else if (j < 133120) {          // sumsq_q 4*512
      long r = j - 131072; *(float4*)(ssq + r) = z; *(float4*)(ssq + r + 4) = z;
    } else {                          // sumsq_k 4*512
      long r = j - 133120; *(float4*)(ssk + r) = z; *(float4*)(ssk + r + 4) = z;
    }
  }
}

// ---------------------------------------------------------------------------
// bf16 NT-GEMM mainloop v6: A (Mx512 rm), B (Nx512 rm = B^T), 128x128 tile,
// BK=32, 16 K-iters, 256 threads = 4 waves, per-wave 64x64 quadrant as
// 4x4 MFMA 16x16x32 frags. 3-deep LDS pipeline, counted vmcnt (as v5).
// v6 change: CONFLICT-FREE swizzle for the 64B-row-stride layout. v5 used
// slot = kq^(row&3): bank-quad = 4*(row&1)+slot repeats every 4 rows ->
// 4-way conflict within a quarter-wave (measured 1.26e7). v6 uses
// slot = kq^((row>>1)&3): quad = 4*(row&1)+slot is 2-to-1 over 16 rows ->
// 2 lanes/quad = free (m136). Stage side mirrors it (same involution):
// LDS[row][slot] holds global chunk [row][slot ^ ((row>>1)&3)].
// Numerics: K ascending, unchanged -> bit-identical.
// ---------------------------------------------------------------------------
__device__ __forceinline__ void gemm_tile_mainloop(
    const bf16* __restrict__ A, const bf16* __restrict__ B,
    int m0, int n0, bf16* As, bf16* Bs, f32x4 acc[4][4])
{
  int tid = threadIdx.x;
  int lane = tid & 63, wave = tid >> 6;
  int wy = wave >> 1, wx = wave & 1;
  // staging: chunk c = issue*256 + tid; row = c>>2 (0..63/issue), slot = c&3.
  int srow = tid >> 2;                       // 0..63
  int scol = ((tid & 3) ^ ((tid >> 3) & 3)) * 8;   // swizzled global col (elems)
  const bf16* ag = A + ((size_t)(m0 + srow) << 9) + scol;
  const bf16* bg = B + ((size_t)(n0 + srow) << 9) + scol;
  bf16* lA = As + wave * 512;   // GLL dest: wave-base + lane*16B; issue +2048
  bf16* lB = Bs + wave * 512;
  int mloc = lane & 15;
  int kq = lane >> 4;                        // k-chunk 0..3 within BK=32

  // tile t: global k-offset t*32; buffer t%3 at element offset (t%3)*4096.
#define STG(t) do { \
    GLL(ag + (t) * 32,         lA + ((t) % 3) * 4096);        \
    GLL(ag + (t) * 32 + 32768, lA + ((t) % 3) * 4096 + 2048); \
    GLL(bg + (t) * 32,         lB + ((t) % 3) * 4096);        \
    GLL(bg + (t) * 32 + 32768, lB + ((t) % 3) * 4096 + 2048); \
  } while (0)

  // prologue: stage tiles 0 and 1; wait tile0 landed (4 of 8 outstanding).
  STG(0);
  STG(1);
  WAIT_VMC(4);
  BARRIER_FENCE();

#pragma unroll
  for (int t = 0; t < 16; ++t) {
    if (t + 2 < 16) STG(t + 2);
    const bf16* Ac = As + (t % 3) * 4096;
    const bf16* Bc = Bs + (t % 3) * 4096;
    bf16x8 af[4], bfr[4];
#pragma unroll
    for (int tt = 0; tt < 4; tt++) {
      int arow = wy * 64 + tt * 16 + mloc;
      af[tt] = *(const bf16x8*)&Ac[arow * 32 + ((kq ^ ((arow >> 1) & 3)) << 3)];
      int brow = wx * 64 + tt * 16 + mloc;
      bfr[tt] = *(const bf16x8*)&Bc[brow * 32 + ((kq ^ ((brow >> 1) & 3)) << 3)];
    }
    WAIT_LGKM0();
    __builtin_amdgcn_s_setprio(1);
#pragma unroll
    for (int ty = 0; ty < 4; ty++)
#pragma unroll
      for (int tx = 0; tx < 4; tx++)
        acc[ty][tx] = __builtin_amdgcn_mfma_f32_16x16x32_bf16(
            af[ty], bfr[tx], acc[ty][tx], 0, 0, 0);
    __builtin_amdgcn_s_setprio(0);
    if (t <= 13)      { WAIT_VMC(4); }   // tile t+1 landed; t+2 in flight
    else if (t == 14) { WAIT_VMC(0); }   // tail: only tile 15 outstanding
    if (t < 15) BARRIER_FENCE();
  }
#undef STG
}

// K1: QKV projection. N-cols [0,512)=q, [512,1024)=k, [1024,1536)=v (v scaled
// by illu). q/k written TRANSPOSED: qbT/kbT[b][c][n] (c stride 16384, n
// contiguous) — sole consumer attn_dots needs n-contiguity for MFMA frags.
// v stays [n][512] row-major (conv/gemm_out need it). Fused column
// sum-of-squares of fp32 q/k accumulators via shuffle + atomicAdd.
__global__ __launch_bounds__(256, 3) void gemm_qkv_kernel(
    const bf16* __restrict__ xb, const bf16* __restrict__ wqkv,
    const float* __restrict__ illu,
    bf16* __restrict__ qbT, bf16* __restrict__ kbT, bf16* __restrict__ vb,
    float* __restrict__ ssq, float* __restrict__ ssk)
{
  __shared__ __align__(16) bf16 As[12288];   // 3 x 4096 (3-deep pipeline)
  __shared__ __align__(16) bf16 Bs[12288];
  int bid = blockIdx.x;
  int xcd = bid & 7, s = bid >> 3;          // s in [0,768)
  int mt = xcd * 64 + s / 12, nt = s % 12;
  int m0 = mt * 128, n0 = nt * 128;
  f32x4 acc[4][4] = {};
  gemm_tile_mainloop(xb, wqkv, m0, n0, As, Bs, acc);

  int tid = threadIdx.x, lane = tid & 63, wave = tid >> 6;
  int wy = wave >> 1, wx = wave & 1;
  int r0 = m0 + wy * 64 + ((lane >> 4) << 2);
  int c0 = n0 + wx * 64 + (lane & 15);
  int region = n0 >> 9;   // tile never crosses a 512-col boundary
  if (region < 2) {
    bf16* outp = region ? kbT : qbT;
    float* dst = (region ? ssk : ssq) + (m0 >> 14) * 512;
    int bb = r0 >> 14;            // batch (tile never crosses 16384 boundary)
    int nl0 = r0 & 16383;
#pragma unroll
    for (int tx = 0; tx < 4; tx++) {
      int lc = (c0 + tx * 16) & 511;
      bf16* colp = outp + (((size_t)bb << 23) + ((size_t)lc << 14));
      float ss = 0.f;
#pragma unroll
      for (int ty = 0; ty < 4; ty++) {
        f32x4 a = acc[ty][tx];
        ss += a[0] * a[0] + a[1] * a[1] + a[2] * a[2] + a[3] * a[3];
        bf16x4 o;
        o[0] = (bf16)a[0]; o[1] = (bf16)a[1]; o[2] = (bf16)a[2]; o[3] = (bf16)a[3];
        *(bf16x4*)&colp[nl0 + ty * 16] = o;
      }
      ss += __shfl_xor(ss, 16);
      ss += __shfl_xor(ss, 32);
      if ((lane >> 4) == 0) atomicAdd(dst + lc, ss);
    }
  } else {
#pragma unroll
    for (int tx = 0; tx < 4; tx++) {
      int lc = (c0 + tx * 16) & 511;
#pragma unroll
      for (int ty = 0; ty < 4; ty++) {
#pragma unroll
        for (int r = 0; r < 4; r++) {
          size_t idx = ((size_t)(r0 + ty * 16 + r) << 9) + lc;
          vb[idx] = (bf16)(acc[ty][tx][r] * illu[idx]);
        }
      }
    }
  }
}

// K3: MFMA attn dots. S[b,h,d,e] = sum_n kbT[b,h*64+d,n] * qbT[b,h*64+e,n]
// — a pure NT-GEMM (both operands n-contiguous). grid (32 bh, 16 n-splits),
// 256 thr = 4 INDEPENDENT waves (no barriers): each wave owns 256 n in 4
// iters of 64, private 8KB k/q LDS tiles (single-buffered; GLL self-synced
// via vmcnt). atomicAdd fp32 partials (attn pre-zeroed by prep).
__global__ __launch_bounds__(256) void attn_dots_kernel(
    const bf16* __restrict__ qbT, const bf16* __restrict__ kbT,
    float* __restrict__ attn)
{
  __shared__ __align__(16) bf16 ks[4][4096];
  __shared__ __align__(16) bf16 qs[4][4096];
  int bh = blockIdx.x, sp = blockIdx.y;
  int b = bh >> 3, h = bh & 7;
  int t = threadIdx.x, lane = t & 63, w = t >> 6;
  size_t base = ((size_t)b << 23) + ((size_t)h << 20);   // [b][c=h*64][n]
  int n0 = sp * 1024 + w * 256;
  int srow = lane >> 3;                         // 8 rows per GLL issue
  int scol = ((lane & 7) ^ (srow & 7)) << 3;    // swizzled n-chunk (elements)
  const bf16* kg = kbT + base + (size_t)srow * 16384 + n0 + scol;
  const bf16* qg = qbT + base + (size_t)srow * 16384 + n0 + scol;
  bf16* lk = &ks[w][0];
  bf16* lq = &qs[w][0];
  int mloc = lane & 15, kq = lane >> 4;
  f32x4 acc[4][4] = {};

  for (int it = 0; it < 4; ++it) {
    WAIT_LGKM0();   // prior iter's ds_reads complete before LDS overwrite
#pragma unroll
    for (int i = 0; i < 8; ++i) {
      GLL(kg + it * 64 + (size_t)i * 131072, lk + i * 512);
      GLL(qg + it * 64 + (size_t)i * 131072, lq + i * 512);
    }
    WAIT_VMC(0);    // staged tiles visible (same-wave, no barrier needed)
    bf16x8 af[4][2], bfq[4][2];
#pragma unroll
    for (int tt = 0; tt < 4; ++tt) {
      int r = tt * 16 + mloc;
#pragma unroll
      for (int kh = 0; kh < 2; ++kh) {
        int slot = (kh * 4 + kq) ^ (r & 7);
        af[tt][kh]  = *(const bf16x8*)&lk[r * 64 + slot * 8];
        bfq[tt][kh] = *(const bf16x8*)&lq[r * 64 + slot * 8];
      }
    }
#pragma unroll
    for (int kh = 0; kh < 2; ++kh)
#pragma unroll
      for (int ta = 0; ta < 4; ++ta)
#pragma unroll
        for (int tb = 0; tb < 4; ++tb)
          acc[ta][tb] = __builtin_amdgcn_mfma_f32_16x16x32_bf16(
              af[ta][kh], bfq[tb][kh], acc[ta][tb], 0, 0, 0);
  }
  float* ap = attn + ((size_t)bh << 12);
  int rr = (lane >> 4) << 2, cc = lane & 15;
#pragma unroll
  for (int ta = 0; ta < 4; ++ta)
#pragma unroll
    for (int tb = 0; tb < 4; ++tb)
#pragma unroll
      for (int r = 0; r < 4; ++r)
        atomicAdd(&ap[(ta * 16 + rr + r) * 64 + tb * 16 + cc], acc[ta][tb][r]);
}

// K4a: logits = S * rescale[h] / (nk[d] * nq[e]); softmax over e. In place.
// one block per (bh, d) row -> 2048 independent waves.
__global__ __launch_bounds__(64) void softmax_kernel(
    float* __restrict__ attn, const float* __restrict__ ssq,
    const float* __restrict__ ssk, const float* __restrict__ rescale)
{
  int bh = blockIdx.x, d = blockIdx.y;
  int b = bh >> 3, h = bh & 7;
  int e = threadIdx.x;
  float nq = fmaxf(sqrtf(ssq[b * 512 + h * 64 + e]), 1e-12f);
  float nk = fmaxf(sqrtf(ssk[b * 512 + h * 64 + d]), 1e-12f);
  float* ap = attn + ((size_t)bh << 12) + d * 64;
  float v = ap[e] * rescale[h] / (nk * nq);
  float m = v;
  for (int o = 32; o > 0; o >>= 1) m = fmaxf(m, __shfl_xor(m, o));
  float ex = expf(v - m);
  float s = ex;
  for (int o = 32; o > 0; o >>= 1) s += __shfl_xor(s, o);
  ap[e] = ex / s;
}

// K4b: W_effT[b][co][h*64+e] = sum_d attn[b,h,d,e] * Wp[co, h*64+d]  (bf16).
// (exact reassociation of xo@Wp^T; out_c = v @ W_eff + bp)
__global__ __launch_bounds__(256) void weff_kernel(
    const float* __restrict__ attn, const float* __restrict__ Wp,
    bf16* __restrict__ wefT)
{
  int cog = blockIdx.x, h = blockIdx.y, b = blockIdx.z;
  __shared__ float at[4096];   // [d][e]
  __shared__ float wp[4096];   // [co_l][d]
  int t = threadIdx.x;
  const float* ap = attn + ((size_t)(b * 8 + h) << 12);
  for (int i = t; i < 4096; i += 256) at[i] = ap[i];
  for (int i = t; i < 4096; i += 256) {
    int r = i >> 6, d = i & 63;
    wp[i] = Wp[((size_t)(cog * 64 + r) << 9) + h * 64 + d];
  }
  __syncthreads();
  int co_l = (t & 15) * 4, e_l = (t >> 4) * 4;
  float acc[16] = {0};
  for (int d = 0; d < 64; d++) {
    float w0 = wp[(co_l + 0) * 64 + d];
    float w1 = wp[(co_l + 1) * 64 + d];
    float w2 = wp[(co_l + 2) * 64 + d];
    float w3 = wp[(co_l + 3) * 64 + d];
    float4 av = *(const float4*)&at[d * 64 + e_l];
    acc[0]  += w0 * av.x; acc[1]  += w0 * av.y; acc[2]  += w0 * av.z; acc[3]  += w0 * av.w;
    acc[4]  += w1 * av.x; acc[5]  += w1 * av.y; acc[6]  += w1 * av.z; acc[7]  += w1 * av.w;
    acc[8]  += w2 * av.x; acc[9]  += w2 * av.y; acc[10] += w2 * av.z; acc[11] += w2 * av.w;
    acc[12] += w3 * av.x; acc[13] += w3 * av.y; acc[14] += w3 * av.z; acc[15] += w3 * av.w;
  }
#pragma unroll
  for (int i = 0; i < 4; i++)
#pragma unroll
    for (int j = 0; j < 4; j++)
      wefT[((size_t)b << 18) + ((size_t)(cog * 64 + co_l + i) << 9) + h * 64 + e_l + j] =
          (bf16)acc[i * 4 + j];
}

// K5: out_c = v @ W_eff[b] + bp  -> d_out (fp32). Same v6 mainloop as K1.
// XCD swizzle: the 4 nt-siblings of an mt share one XCD.
__global__ __launch_bounds__(256, 3) void gemm_out_kernel(
    const bf16* __restrict__ vb, const bf16* __restrict__ wefT,
    const float* __restrict__ bp, float* __restrict__ out)
{
  __shared__ __align__(16) bf16 As[12288];
  __shared__ __align__(16) bf16 Bs[12288];
  int b = blockIdx.y;
  int bid = blockIdx.x;
  int xcd = bid & 7, s = bid >> 3;          // s in [0,64)
  int mt = xcd * 16 + (s >> 2), nt = s & 3;
  int m0 = mt * 128, n0 = nt * 128;
  const bf16* A = vb + ((size_t)b << 23);
  const bf16* B = wefT + ((size_t)b << 18);
  f32x4 acc[4][4] = {};
  gemm_tile_mainloop(A, B, m0, n0, As, Bs, acc);

  int tid = threadIdx.x, lane = tid & 63, wave = tid >> 6;
  int wy = wave >> 1, wx = wave & 1;
  int r0 = (b << 14) + m0 + wy * 64 + ((lane >> 4) << 2);
  int c0 = n0 + wx * 64 + (lane & 15);
#pragma unroll
  for (int ty = 0; ty < 4; ty++) {
#pragma unroll
    for (int tx = 0; tx < 4; tx++) {
      int lc = c0 + tx * 16;
      float bias = bp[lc];
#pragma unroll
      for (int r = 0; r < 4; r++) {
        int grow = r0 + ty * 16 + r;
        out[((size_t)grow << 9) + lc] = acc[ty][tx][r] + bias;
      }
    }
  }
}

// K6 (fused conv1+conv2): per block, 8x8 output tile x 128-channel slice.
// Phase 1: p = gelu_erf(dwconv3x3(v, pe1)) on the 10x10 halo -> LDS (25.6KB).
// Phase 2: out += dwconv3x3(p, pe2) (fp32 RMW). Eliminates the pbuf
// round-trip (~160MB HBM) and one launch. 256 thr = 16 ch-groups x 16 sp.
// p outside the image is 0 (SAME zero-pad for both convs).
__global__ __launch_bounds__(256) void conv_fused_kernel(
    const bf16* __restrict__ vb, const float* __restrict__ pe1,
    const float* __restrict__ pe2, float* __restrict__ out)
{
  __shared__ __align__(16) bf16 ps[10 * 10 * 128];
  int b = blockIdx.z;
  int cs = blockIdx.y;                 // channel slice 0..3
  int tile = blockIdx.x;               // 0..255
  int y0 = (tile >> 4) * 8, x0 = (tile & 15) * 8;
  int t = threadIdx.x;
  int cl = (t & 15) * 8;               // channel within slice
  int cg = cs * 128 + cl;              // global channel
  int sp = t >> 4;                     // 0..15
  const bf16* vbase = vb + ((size_t)b << 23);

  {
    float w1[72];
#pragma unroll
    for (int i = 0; i < 8; i++)
#pragma unroll
      for (int k = 0; k < 9; k++)
        w1[i * 9 + k] = pe1[(cg + i) * 9 + k];
    for (int pos = sp; pos < 100; pos += 16) {
      int py = pos / 10, px = pos % 10;
      int yy = y0 - 1 + py, xx = x0 - 1 + px;
      bf16x8 o;
      if (yy >= 0 && yy < 128 && xx >= 0 && xx < 128) {
        float a[8] = {0, 0, 0, 0, 0, 0, 0, 0};
#pragma unroll
        for (int ky = 0; ky < 3; ky++) {
          int sy = yy + ky - 1;
          if (sy < 0 || sy >= 128) continue;
#pragma unroll
          for (int kx = 0; kx < 3; kx++) {
            int sx = xx + kx - 1;
            if (sx < 0 || sx >= 128) continue;
            bf16x8 vv = *(const bf16x8*)&vbase[((size_t)(sy * 128 + sx) << 9) + cg];
#pragma unroll
            for (int i = 0; i < 8; i++) a[i] += (float)vv[i] * w1[i * 9 + ky * 3 + kx];
          }
        }
#pragma unroll
        for (int i = 0; i < 8; i++) {
          float g = 0.5f * a[i] * (1.0f + erff(a[i] * 0.70710678118654752f));
          o[i] = (bf16)g;
        }
      } else {
#pragma unroll
        for (int i = 0; i < 8; i++) o[i] = (bf16)0.0f;
      }
      *(bf16x8*)&ps[(py * 10 + px) * 128 + cl] = o;
    }
  }
  __syncthreads();

  float w2[72];
#pragma unroll
  for (int i = 0; i < 8; i++)
#pragma unroll
    for (int k = 0; k < 9; k++)
      w2[i * 9 + k] = pe2[(cg + i) * 9 + k];
  float* ob = out + ((size_t)b << 23);
  for (int o = sp; o < 64; o += 16) {
    int oy = o >> 3, ox = o & 7;
    float a[8] = {0, 0, 0, 0, 0, 0, 0, 0};
#pragma unroll
    for (int ky = 0; ky < 3; ky++)
#pragma unroll
      for (int kx = 0; kx < 3; kx++) {
        bf16x8 pv = *(const bf16x8*)&ps[((oy + ky) * 10 + (ox + kx)) * 128 + cl];
#pragma unroll
        for (int i = 0; i < 8; i++) a[i] += (float)pv[i] * w2[i * 9 + ky * 3 + kx];
      }
    size_t oi = ((size_t)((y0 + oy) * 128 + (x0 + ox)) << 9) + cg;
    float4 o0 = *(float4*)&ob[oi];
    float4 o1 = *(float4*)&ob[oi + 4];
    o0.x += a[0]; o0.y += a[1]; o0.z += a[2]; o0.w += a[3];
    o1.x += a[4]; o1.y += a[5]; o1.z += a[6]; o1.w += a[7];
    *(float4*)&ob[oi] = o0;
    *(float4*)&ob[oi + 4] = o1;
  }
}

extern "C" void kernel_launch(void* const* d_in, const int* in_sizes, int n_in,
                              void* d_out, int out_size, void* d_ws, size_t ws_size,
                              hipStream_t stream) {
  (void)in_sizes; (void)n_in; (void)out_size; (void)ws_size;
  const float* x       = (const float*)d_in[0];
  const float* illu    = (const float*)d_in[1];
  const float* Wq      = (const float*)d_in[2];
  const float* Wk      = (const float*)d_in[3];
  const float* Wv      = (const float*)d_in[4];
  const float* rescale = (const float*)d_in[5];
  const float* Wp      = (const float*)d_in[6];
  const float* bp      = (const float*)d_in[7];
  const float* pe1     = (const float*)d_in[8];
  const float* pe2     = (const float*)d_in[9];
  float* out = (float*)d_out;
  char* ws = (char*)d_ws;

  // workspace layout (bytes); total = 272,646,144
  bf16*  xb   = (bf16*)(ws);                      // 67,108,864
  bf16*  wqkv = (bf16*)(ws + 67108864);           //  1,572,864
  bf16*  qbT  = (bf16*)(ws + 68681728);           // 67,108,864  [b][c][n]
  bf16*  kbT  = (bf16*)(ws + 135790592);          // 67,108,864  [b][c][n]
  bf16*  vb   = (bf16*)(ws + 202899456);          // 67,108,864
  float* ssq  = (float*)(ws + 270008320);         //      8,192
  float* ssk  = (float*)(ws + 270016512);         //      8,192
  float* attn = (float*)(ws + 270024704);         //    524,288
  bf16*  wefT = (bf16*)(ws + 270548992);          //  2,097,152

  prep_kernel<<<16834, 256, 0, stream>>>(x, Wq, Wk, Wv, xb, wqkv, attn, ssq, ssk);
  gemm_qkv_kernel<<<6144, 256, 0, stream>>>(xb, wqkv, illu, qbT, kbT, vb, ssq, ssk);
  attn_dots_kernel<<<dim3(32, 16), 256, 0, stream>>>(qbT, kbT, attn);
  softmax_kernel<<<dim3(32, 64), 64, 0, stream>>>(attn, ssq, ssk, rescale);
  weff_kernel<<<dim3(8, 8, 4), 256, 0, stream>>>(attn, Wp, wefT);
  gemm_out_kernel<<<dim3(512, 4), 256, 0, stream>>>(vb, wefT, bp, out);
  conv_fused_kernel<<<dim3(256, 4, 4), 256, 0, stream>>>(vb, pe1, pe2, out);
}